// Round 6
// baseline (140.429 us; speedup 1.0000x reference)
//
#include <hip/hip_runtime.h>

typedef __attribute__((ext_vector_type(8))) short bf16x8;
typedef __attribute__((ext_vector_type(4))) float f32x4;
typedef __attribute__((ext_vector_type(16))) float f32x16;
typedef __attribute__((ext_vector_type(4))) short short4v;
typedef __attribute__((ext_vector_type(4))) unsigned int uint4v;

#define B_  2
#define T_  2048
#define D_  1024
#define H_  16
#define HD_ 64

__device__ inline short f2bf(float f){
  unsigned u = __builtin_bit_cast(unsigned, f);
  u += 0x7fff + ((u >> 16) & 1);          // round-to-nearest-even
  return (short)(u >> 16);
}

__device__ inline void gl2lds16(const void* g, void* l){
  __builtin_amdgcn_global_load_lds(
      (const __attribute__((address_space(1))) unsigned int*)g,
      (__attribute__((address_space(3))) unsigned int*)l, 16, 0, 0);
}

// ---------------- elementwise f32 -> bf16 ----------------
__global__ __launch_bounds__(256) void convert_f32_bf16(
    const float* __restrict__ in, short* __restrict__ out){
  int i = (blockIdx.x * 256 + threadIdx.x) * 4;
  float4 v = *(const float4*)(in + i);
  short4v o;
  o[0] = f2bf(v.x); o[1] = f2bf(v.y); o[2] = f2bf(v.z); o[3] = f2bf(v.w);
  *(short4v*)(out + i) = o;
}

// ---------------- f32 [R][C] -> bf16 [C][R] ----------------
__global__ __launch_bounds__(256) void transpose_f32_bf16(
    const float* __restrict__ in, short* __restrict__ out, int R, int C){
  __shared__ float tile[32][33];
  int tx = threadIdx.x & 31, ty0 = threadIdx.x >> 5;
  int bx = blockIdx.x << 5, by = blockIdx.y << 5;
#pragma unroll
  for (int i = 0; i < 4; i++){
    int ty = ty0 + i * 8;
    tile[ty][tx] = in[(by + ty) * C + bx + tx];
  }
  __syncthreads();
#pragma unroll
  for (int i = 0; i < 4; i++){
    int ty = ty0 + i * 8;
    out[(bx + ty) * R + by + tx] = f2bf(tile[tx][ty]);
  }
}

// ---------------- GEMM: C = A[M][K] @ Bt[N][K]^T + bias ----------------
// 2-phase double-buffered pipeline, raw barriers, counted vmcnt (T3+T4).
#define BM 128
#define BN 128
#define BK 32

// Q pre-scale: 1/sqrt(64) * log2(e)  (softmax runs in exp2 domain)
#define QSCALE 0.18033688011112042f

template<int N_, int K_, int EPI>
__global__ __launch_bounds__(256) void gemm_bt(
    const short* __restrict__ A, const short* __restrict__ Bt,
    const float* __restrict__ bias,
    short* __restrict__ q, short* __restrict__ kk, short* __restrict__ vT,
    float* __restrict__ outf){
  __shared__ short As[2][BM * BK];
  __shared__ short Bs[2][BN * BK];
  const int tid = threadIdx.x;
  const int lane = tid & 63, w = tid >> 6;
  const int wm = w >> 1, wn = w & 1;
  const int lr = lane & 15, lk = lane >> 4;
  const int brow = blockIdx.y * BM, bcol = blockIdx.x * BN;
  f32x4 acc[4][4] = {};
  const short* Ag = A  + brow * K_;
  const short* Bg = Bt + bcol * K_;

  auto stage = [&](int buf, int k0){
#pragma unroll
    for (int i = 0; i < 2; i++){
      int idx = i * 256 + tid;
      int row = idx >> 2, c8 = (idx & 3) * 8;   // 64B rows of 32 bf16
      gl2lds16(Ag + row * K_ + k0 + c8, (char*)As[buf] + idx * 16);
      gl2lds16(Bg + row * K_ + k0 + c8, (char*)Bs[buf] + idx * 16);
    }
  };

  const int NT = K_ / BK;
  stage(0, 0);
  for (int t = 0; t < NT; ++t){
    const int cur = t & 1;
    if (t + 1 < NT){
      stage(cur ^ 1, (t + 1) * BK);                    // prefetch next K-tile
      asm volatile("s_waitcnt vmcnt(4)" ::: "memory"); // current tile landed
    } else {
      asm volatile("s_waitcnt vmcnt(0)" ::: "memory");
    }
    __builtin_amdgcn_s_barrier();                      // buf[cur] fully staged
    __builtin_amdgcn_sched_barrier(0);

    bf16x8 a[4], b[4];
#pragma unroll
    for (int mf = 0; mf < 4; mf++)
      a[mf] = *(const bf16x8*)(As[cur] + (wm * 64 + mf * 16 + lr) * BK + lk * 8);
#pragma unroll
    for (int nf = 0; nf < 4; nf++)
      b[nf] = *(const bf16x8*)(Bs[cur] + (wn * 64 + nf * 16 + lr) * BK + lk * 8);
    __builtin_amdgcn_s_setprio(1);
#pragma unroll
    for (int mf = 0; mf < 4; mf++)
#pragma unroll
      for (int nf = 0; nf < 4; nf++)
        acc[mf][nf] = __builtin_amdgcn_mfma_f32_16x16x32_bf16(a[mf], b[nf], acc[mf][nf], 0, 0, 0);
    __builtin_amdgcn_s_setprio(0);
    __builtin_amdgcn_sched_barrier(0);
    __builtin_amdgcn_s_barrier();                      // reads of buf[cur] done
  }

  if constexpr (EPI == 0){
    // C/D layout: col = lane&15, row = (lane>>4)*4 + r
#pragma unroll
    for (int nf = 0; nf < 4; nf++){
      int n = bcol + wn * 64 + nf * 16 + lr;
      float bv = bias[n];
      int sec = n >> 10, d = n & 1023, h = d >> 6, hd = d & 63;
#pragma unroll
      for (int mf = 0; mf < 4; mf++){
        int m0 = brow + wm * 64 + mf * 16 + lk * 4;
        int b = m0 >> 11, t0 = m0 & 2047;
        int bh = b * H_ + h;
        if (sec == 0){
#pragma unroll
          for (int r = 0; r < 4; r++)
            q[(bh * T_ + t0 + r) * HD_ + hd] = f2bf((acc[mf][nf][r] + bv) * QSCALE);
        } else if (sec == 1){
#pragma unroll
          for (int r = 0; r < 4; r++)
            kk[(bh * T_ + t0 + r) * HD_ + hd] = f2bf(acc[mf][nf][r] + bv);
        } else {
          float v0 = acc[mf][nf][0] + bv, v1 = acc[mf][nf][1] + bv;
          float v2 = acc[mf][nf][2] + bv, v3 = acc[mf][nf][3] + bv;
          unsigned lo = (unsigned)(unsigned short)f2bf(v0) | ((unsigned)(unsigned short)f2bf(v1) << 16);
          unsigned hi = (unsigned)(unsigned short)f2bf(v2) | ((unsigned)(unsigned short)f2bf(v3) << 16);
          uint2 pk; pk.x = lo; pk.y = hi;
          *(uint2*)(vT + (bh * HD_ + hd) * T_ + t0) = pk;   // v stored transposed [B,H,hd,T]
        }
      }
    }
  } else {
#pragma unroll
    for (int nf = 0; nf < 4; nf++){
      int n = bcol + wn * 64 + nf * 16 + lr;
      float bv = bias[n];
#pragma unroll
      for (int mf = 0; mf < 4; mf++){
        int m0 = brow + wm * 64 + mf * 16 + lk * 4;
#pragma unroll
        for (int r = 0; r < 4; r++)
          outf[(m0 + r) * N_ + n] = acc[mf][nf][r] + bv;
      }
    }
  }
}

// ---------------- causal flash attention, 32x32 swapped-QK^T ----------------
// Q,K: [B*H, T, 64] bf16 (Q pre-scaled by QSCALE => logits in exp2 domain)
// Vt: [B*H, 64, T] bf16;  Y: [B*T, 1024] bf16.
// Grid: 512 blocks x 4 waves. Block bx -> q-tile i (128 rows), bh = bx&31.
// Blocks c and c+256 get tile sizes summing constant -> uniform CU load.
// Phase = 128 kv (two 64-kv sub-tiles) per barrier pair: halves sync count,
// amortizes softmax reduce, batches 8 global_load_lds (vmcnt(8) counted).
__global__ __launch_bounds__(256) void attn32(
    const short* __restrict__ Q, const short* __restrict__ Kg,
    const short* __restrict__ Vt, short* __restrict__ Y){
  __shared__ short Ks[2][2][64 * 64];
  __shared__ short Vs[2][2][64 * 64];
  __shared__ float bounce[4][32];
  const int tid = threadIdx.x;
  const int w = tid >> 6, l = tid & 63;
  const int lq = l & 31, h = l >> 5;
  const int bx = blockIdx.x;
  const int i = (bx < 256) ? 15 - (bx >> 5) : (bx >> 5) - 8;
  const int bh = bx & 31;
  const int q0 = i * 128, qw = q0 + w * 32;
  const int np = i + 1;                     // phases of 128 kv

  // Q fragments (B-operand): qb[dk] = Q[qw+lq][16*dk + 8*h .. +7]
  bf16x8 qb[4];
  {
    const short* qbase = Q + (bh * T_ + qw + lq) * HD_;
#pragma unroll
    for (int dk = 0; dk < 4; dk++)
      qb[dk] = *(const bf16x8*)(qbase + dk * 16 + h * 8);
  }

  f32x16 o0 = {}, o1 = {};
  float m = -1e30f, ll = 0.f;

  auto stage = [&](int buf, int p){
#pragma unroll
    for (int s2 = 0; s2 < 2; s2++){
      int t = 2 * p + s2;
#pragma unroll
      for (int j = 0; j < 2; j++){
        int idx = j * 256 + tid;
        int row = idx >> 3, cb = (idx & 7) * 16;     // 128B rows
        int cbs = cb ^ ((row & 7) << 4);
        gl2lds16(Kg + (bh * T_ + t * 64 + row) * HD_ + (cbs >> 1), (char*)Ks[buf][s2] + idx * 16);
        gl2lds16(Vt + (bh * HD_ + row) * T_ + t * 64 + (cbs >> 1), (char*)Vs[buf][s2] + idx * 16);
      }
    }
  };

  stage(0, 0);
  for (int p = 0; p < np; ++p){
    const int cur = p & 1;
    if (p + 1 < np){
      stage(cur ^ 1, p + 1);                            // prefetch next phase
      asm volatile("s_waitcnt vmcnt(8)" ::: "memory");  // current phase landed
    } else {
      asm volatile("s_waitcnt vmcnt(0)" ::: "memory");
    }
    __builtin_amdgcn_s_barrier();
    __builtin_amdgcn_sched_barrier(0);

    const int kvb0 = p * 128;                // sub0 always active (kvb0 <= q0 <= qw)
    const bool act1 = (kvb0 + 64 <= qw + 31);
    const int qg = qw + lq;

    // S^T = K . Q^T over up to 128 kv: s4[s2*2+kb] covers kv kvb0+64*s2+32*kb
    f32x16 s4[4] = {};
    __builtin_amdgcn_s_setprio(1);
#pragma unroll
    for (int kb = 0; kb < 2; kb++){
      int row = kb * 32 + lq;
      const char* rp = (const char*)Ks[cur][0] + row * 128;
      int swz = (row & 7) << 4;
#pragma unroll
      for (int dk = 0; dk < 4; dk++){
        bf16x8 ka = *(const bf16x8*)(rp + ((dk * 32 + h * 16) ^ swz));
        s4[kb] = __builtin_amdgcn_mfma_f32_32x32x16_bf16(ka, qb[dk], s4[kb], 0, 0, 0);
      }
    }
    if (act1){
#pragma unroll
      for (int kb = 0; kb < 2; kb++){
        int row = kb * 32 + lq;
        const char* rp = (const char*)Ks[cur][1] + row * 128;
        int swz = (row & 7) << 4;
#pragma unroll
        for (int dk = 0; dk < 4; dk++){
          bf16x8 ka = *(const bf16x8*)(rp + ((dk * 32 + h * 16) ^ swz));
          s4[2 + kb] = __builtin_amdgcn_mfma_f32_32x32x16_bf16(ka, qb[dk], s4[2 + kb], 0, 0, 0);
        }
      }
    }
    __builtin_amdgcn_s_setprio(0);

    // causal mask per sub-tile
    if (kvb0 + 63 > qw){
#pragma unroll
      for (int kb = 0; kb < 2; kb++)
#pragma unroll
        for (int r = 0; r < 16; r++){
          int kv = kvb0 + kb * 32 + (r & 3) + 8 * (r >> 2) + 4 * h;
          if (kv > qg) s4[kb][r] = -1e30f;
        }
    }
    if (act1 && kvb0 + 127 > qw){
#pragma unroll
      for (int kb = 0; kb < 2; kb++)
#pragma unroll
        for (int r = 0; r < 16; r++){
          int kv = kvb0 + 64 + kb * 32 + (r & 3) + 8 * (r >> 2) + 4 * h;
          if (kv > qg) s4[2 + kb][r] = -1e30f;
        }
    }

    // row max: elementwise vector max + 4-level tree + 1 cross-half shuffle
    float vm[16];
#pragma unroll
    for (int r = 0; r < 16; r++) vm[r] = fmaxf(s4[0][r], s4[1][r]);
    if (act1){
#pragma unroll
      for (int r = 0; r < 16; r++) vm[r] = fmaxf(vm[r], fmaxf(s4[2][r], s4[3][r]));
    }
#pragma unroll
    for (int st = 8; st > 0; st >>= 1)
#pragma unroll
      for (int r = 0; r < st; r++) vm[r] = fmaxf(vm[r], vm[r + st]);
    float pm = fmaxf(vm[0], __shfl_xor(vm[0], 32));

    // defer-max (T13): rescale O only when max grew > 8 (log2 domain)
    if (__any(pm > m + 8.f)){
      float mn = fmaxf(pm, m);
      float sf = __builtin_amdgcn_exp2f(m - mn);
      m = mn;
      ll *= sf;
      bounce[w][lq] = sf;                 // lanes l and l+32 write same value
#pragma unroll
      for (int r = 0; r < 16; r++){
        float sr = bounce[w][(r & 3) + 8 * (r >> 2) + 4 * h];
        o0[r] *= sr; o1[r] *= sr;
      }
    }

    // P = 2^(s - m); row sum over active subs
    float ts = 0.f;
#pragma unroll
    for (int kb = 0; kb < 2; kb++)
#pragma unroll
      for (int r = 0; r < 16; r++){
        float pv = __builtin_amdgcn_exp2f(s4[kb][r] - m);
        s4[kb][r] = pv;
        ts += pv;
      }
    if (act1){
#pragma unroll
      for (int kb = 2; kb < 4; kb++)
#pragma unroll
        for (int r = 0; r < 16; r++){
          float pv = __builtin_amdgcn_exp2f(s4[kb][r] - m);
          s4[kb][r] = pv;
          ts += pv;
        }
    }
    ts += __shfl_xor(ts, 32);
    ll += ts;

    // pack + PV per active sub-tile
#pragma unroll
    for (int s2 = 0; s2 < 2; s2++){
      if (s2 == 0 || act1){
        unsigned pw0[8], pw1[8];
#pragma unroll
        for (int kb = 0; kb < 2; kb++)
#pragma unroll
          for (int gg = 0; gg < 4; gg++){
            unsigned r0, r1;
            asm("v_cvt_pk_bf16_f32 %0, %1, %2" : "=v"(r0)
                : "v"(s4[s2 * 2 + kb][gg * 4 + 0]), "v"(s4[s2 * 2 + kb][gg * 4 + 1]));
            asm("v_cvt_pk_bf16_f32 %0, %1, %2" : "=v"(r1)
                : "v"(s4[s2 * 2 + kb][gg * 4 + 2]), "v"(s4[s2 * 2 + kb][gg * 4 + 3]));
            pw0[kb * 4 + gg] = r0;
            pw1[kb * 4 + gg] = r1;
          }
        // swap(D=even, S=odd): D_hi <-> S_lo. even reg -> A-word0, odd -> A-word2.
#pragma unroll
        for (int ks = 0; ks < 4; ks++){
          asm("v_permlane32_swap_b32 %0, %1" : "+v"(pw0[2 * ks]), "+v"(pw0[2 * ks + 1]));
          asm("v_permlane32_swap_b32 %0, %1" : "+v"(pw1[2 * ks]), "+v"(pw1[2 * ks + 1]));
        }

        __builtin_amdgcn_s_setprio(1);
#pragma unroll
        for (int ks = 0; ks < 4; ks++){
          uint4v paw;
          paw[0] = pw0[2 * ks];     paw[1] = pw1[2 * ks];
          paw[2] = pw0[2 * ks + 1]; paw[3] = pw1[2 * ks + 1];
          bf16x8 pa = __builtin_bit_cast(bf16x8, paw);
#pragma unroll
          for (int nb = 0; nb < 2; nb++){
            int row = nb * 32 + lq;
            bf16x8 vb = *(const bf16x8*)((const char*)Vs[cur][s2] + row * 128 +
                          ((ks * 32 + h * 16) ^ ((row & 7) << 4)));
            if (nb == 0) o0 = __builtin_amdgcn_mfma_f32_32x32x16_bf16(pa, vb, o0, 0, 0, 0);
            else         o1 = __builtin_amdgcn_mfma_f32_32x32x16_bf16(pa, vb, o1, 0, 0, 0);
          }
        }
        __builtin_amdgcn_s_setprio(0);
      }
    }

    __builtin_amdgcn_sched_barrier(0);
    __builtin_amdgcn_s_barrier();        // all reads of buf[cur] done
  }

  // epilogue: normalize by 1/l (broadcast via warp-private LDS) and store
  bounce[w][lq] = __builtin_amdgcn_rcpf(ll);
  const int b = bh >> 4, hh = bh & 15;
#pragma unroll
  for (int r = 0; r < 16; r++){
    int row = (r & 3) + 8 * (r >> 2) + 4 * h;
    float rl = bounce[w][row];
    int qg = qw + row;
    short* yb = Y + (b * T_ + qg) * D_ + hh * 64;
    yb[lq]      = f2bf(o0[r] * rl);
    yb[32 + lq] = f2bf(o1[r] * rl);
  }
}

// ---------------- launch ----------------
extern "C" void kernel_launch(void* const* d_in, const int* in_sizes, int n_in,
                              void* d_out, int out_size, void* d_ws, size_t ws_size,
                              hipStream_t stream) {
  const float* x  = (const float*)d_in[0];
  const float* W1 = (const float*)d_in[1];
  const float* b1 = (const float*)d_in[2];
  const float* W2 = (const float*)d_in[3];
  const float* b2 = (const float*)d_in[4];
  float* out = (float*)d_out;

  char* ws = (char*)d_ws;
  short* W1T = (short*)(ws);                         // [3072][1024] bf16, 6 MB
  short* W2T = (short*)(ws + 6291456);               // [1024][1024] bf16, 2 MB
  short* xb  = (short*)(ws + 8388608);               // [4096][1024] bf16, 8 MB
  short* q   = (short*)(ws + 16777216);              // [B,H,T,64]  bf16, 8 MB
  short* kk  = (short*)(ws + 25165824);              // [B,H,T,64]  bf16, 8 MB
  short* vT  = (short*)(ws + 33554432);              // [B,H,64,T]  bf16, 8 MB
  short* y   = xb;                                   // alias: xb dead after QKV GEMM

  convert_f32_bf16<<<dim3(4096), dim3(256), 0, stream>>>(x, xb);
  transpose_f32_bf16<<<dim3(96, 32), dim3(256), 0, stream>>>(W1, W1T, 1024, 3072);
  transpose_f32_bf16<<<dim3(32, 32), dim3(256), 0, stream>>>(W2, W2T, 1024, 1024);
  gemm_bt<3072, 1024, 0><<<dim3(24, 32), dim3(256), 0, stream>>>(xb, W1T, b1, q, kk, vT, nullptr);
  attn32<<<dim3(512), dim3(256), 0, stream>>>(q, kk, vT, y);
  gemm_bt<1024, 1024, 1><<<dim3(8, 32), dim3(256), 0, stream>>>(y, W2T, b2, nullptr, nullptr, nullptr, out);
}

// Round 7
// 123.411 us; speedup vs baseline: 1.1379x; 1.1379x over previous
//
#include <hip/hip_runtime.h>

typedef __attribute__((ext_vector_type(8))) short bf16x8;
typedef __attribute__((ext_vector_type(4))) float f32x4;
typedef __attribute__((ext_vector_type(16))) float f32x16;
typedef __attribute__((ext_vector_type(4))) short short4v;
typedef __attribute__((ext_vector_type(4))) unsigned int uint4v;

#define B_  2
#define T_  2048
#define D_  1024
#define H_  16
#define HD_ 64

__device__ inline short f2bf(float f){
  unsigned u = __builtin_bit_cast(unsigned, f);
  u += 0x7fff + ((u >> 16) & 1);          // round-to-nearest-even
  return (short)(u >> 16);
}

__device__ inline void gl2lds16(const void* g, void* l){
  __builtin_amdgcn_global_load_lds(
      (const __attribute__((address_space(1))) unsigned int*)g,
      (__attribute__((address_space(3))) unsigned int*)l, 16, 0, 0);
}

// ---------------- elementwise f32 -> bf16 ----------------
__global__ __launch_bounds__(256) void convert_f32_bf16(
    const float* __restrict__ in, short* __restrict__ out){
  int i = (blockIdx.x * 256 + threadIdx.x) * 4;
  float4 v = *(const float4*)(in + i);
  short4v o;
  o[0] = f2bf(v.x); o[1] = f2bf(v.y); o[2] = f2bf(v.z); o[3] = f2bf(v.w);
  *(short4v*)(out + i) = o;
}

// ---------------- f32 [R][C] -> bf16 [C][R] ----------------
__global__ __launch_bounds__(256) void transpose_f32_bf16(
    const float* __restrict__ in, short* __restrict__ out, int R, int C){
  __shared__ float tile[32][33];
  int tx = threadIdx.x & 31, ty0 = threadIdx.x >> 5;
  int bx = blockIdx.x << 5, by = blockIdx.y << 5;
#pragma unroll
  for (int i = 0; i < 4; i++){
    int ty = ty0 + i * 8;
    tile[ty][tx] = in[(by + ty) * C + bx + tx];
  }
  __syncthreads();
#pragma unroll
  for (int i = 0; i < 4; i++){
    int ty = ty0 + i * 8;
    out[(bx + ty) * R + by + tx] = f2bf(tile[tx][ty]);
  }
}

// ---------------- GEMM: C = A[M][K] @ Bt[N][K]^T + bias ----------------
// 2-phase double-buffered pipeline, raw barriers, counted vmcnt (T3+T4).
#define BM 128
#define BN 128
#define BK 32

// Q pre-scale: 1/sqrt(64) * log2(e)  (softmax runs in exp2 domain)
#define QSCALE 0.18033688011112042f

template<int N_, int K_, int EPI>
__global__ __launch_bounds__(256) void gemm_bt(
    const short* __restrict__ A, const short* __restrict__ Bt,
    const float* __restrict__ bias,
    short* __restrict__ q, short* __restrict__ kk, short* __restrict__ vT,
    float* __restrict__ outf){
  __shared__ short As[2][BM * BK];
  __shared__ short Bs[2][BN * BK];
  const int tid = threadIdx.x;
  const int lane = tid & 63, w = tid >> 6;
  const int wm = w >> 1, wn = w & 1;
  const int lr = lane & 15, lk = lane >> 4;
  const int brow = blockIdx.y * BM, bcol = blockIdx.x * BN;
  f32x4 acc[4][4] = {};
  const short* Ag = A  + brow * K_;
  const short* Bg = Bt + bcol * K_;

  auto stage = [&](int buf, int k0){
#pragma unroll
    for (int i = 0; i < 2; i++){
      int idx = i * 256 + tid;
      int row = idx >> 2, c8 = (idx & 3) * 8;   // 64B rows of 32 bf16
      gl2lds16(Ag + row * K_ + k0 + c8, (char*)As[buf] + idx * 16);
      gl2lds16(Bg + row * K_ + k0 + c8, (char*)Bs[buf] + idx * 16);
    }
  };

  const int NT = K_ / BK;
  stage(0, 0);
  for (int t = 0; t < NT; ++t){
    const int cur = t & 1;
    if (t + 1 < NT){
      stage(cur ^ 1, (t + 1) * BK);                    // prefetch next K-tile
      asm volatile("s_waitcnt vmcnt(4)" ::: "memory"); // current tile landed
    } else {
      asm volatile("s_waitcnt vmcnt(0)" ::: "memory");
    }
    __builtin_amdgcn_s_barrier();                      // buf[cur] fully staged
    __builtin_amdgcn_sched_barrier(0);

    bf16x8 a[4], b[4];
#pragma unroll
    for (int mf = 0; mf < 4; mf++)
      a[mf] = *(const bf16x8*)(As[cur] + (wm * 64 + mf * 16 + lr) * BK + lk * 8);
#pragma unroll
    for (int nf = 0; nf < 4; nf++)
      b[nf] = *(const bf16x8*)(Bs[cur] + (wn * 64 + nf * 16 + lr) * BK + lk * 8);
    __builtin_amdgcn_s_setprio(1);
#pragma unroll
    for (int mf = 0; mf < 4; mf++)
#pragma unroll
      for (int nf = 0; nf < 4; nf++)
        acc[mf][nf] = __builtin_amdgcn_mfma_f32_16x16x32_bf16(a[mf], b[nf], acc[mf][nf], 0, 0, 0);
    __builtin_amdgcn_s_setprio(0);
    __builtin_amdgcn_sched_barrier(0);
    __builtin_amdgcn_s_barrier();                      // reads of buf[cur] done
  }

  if constexpr (EPI == 0){
    // C/D layout: col = lane&15, row = (lane>>4)*4 + r
#pragma unroll
    for (int nf = 0; nf < 4; nf++){
      int n = bcol + wn * 64 + nf * 16 + lr;
      float bv = bias[n];
      int sec = n >> 10, d = n & 1023, h = d >> 6, hd = d & 63;
#pragma unroll
      for (int mf = 0; mf < 4; mf++){
        int m0 = brow + wm * 64 + mf * 16 + lk * 4;
        int b = m0 >> 11, t0 = m0 & 2047;
        int bh = b * H_ + h;
        if (sec == 0){
#pragma unroll
          for (int r = 0; r < 4; r++)
            q[(bh * T_ + t0 + r) * HD_ + hd] = f2bf((acc[mf][nf][r] + bv) * QSCALE);
        } else if (sec == 1){
#pragma unroll
          for (int r = 0; r < 4; r++)
            kk[(bh * T_ + t0 + r) * HD_ + hd] = f2bf(acc[mf][nf][r] + bv);
        } else {
          float v0 = acc[mf][nf][0] + bv, v1 = acc[mf][nf][1] + bv;
          float v2 = acc[mf][nf][2] + bv, v3 = acc[mf][nf][3] + bv;
          unsigned lo = (unsigned)(unsigned short)f2bf(v0) | ((unsigned)(unsigned short)f2bf(v1) << 16);
          unsigned hi = (unsigned)(unsigned short)f2bf(v2) | ((unsigned)(unsigned short)f2bf(v3) << 16);
          uint2 pk; pk.x = lo; pk.y = hi;
          *(uint2*)(vT + (bh * HD_ + hd) * T_ + t0) = pk;   // v stored transposed [B,H,hd,T]
        }
      }
    }
  } else {
#pragma unroll
    for (int nf = 0; nf < 4; nf++){
      int n = bcol + wn * 64 + nf * 16 + lr;
      float bv = bias[n];
#pragma unroll
      for (int mf = 0; mf < 4; mf++){
        int m0 = brow + wm * 64 + mf * 16 + lk * 4;
#pragma unroll
        for (int r = 0; r < 4; r++)
          outf[(m0 + r) * N_ + n] = acc[mf][nf][r] + bv;
      }
    }
  }
}

// ---------------- causal flash attention, 32x32 swapped-QK^T ----------------
// Q,K: [B*H, T, 64] bf16 (Q pre-scaled by QSCALE => logits in exp2 domain)
// Vt: [B*H, 64, T] bf16.
// SPLIT=0: grid 512, block bx -> tile i (128 q-rows), full kv range; writes Y.
// SPLIT=1: grid 1024, kv range split in two halves with private online-softmax
//   state; writes unnormalized f32 partials Op + (m,l); merged by attn_merge.
//   Block map: u=bx>>5, v=u&15, i = v<8 ? 15-v : v-8, hf=u>>4 -> each CU's 4
//   resident blocks sum to 34 kv-steps (uniform).
__device__ inline int crow(int r, int h){ return (r & 3) + 8 * (r >> 2) + 4 * h; }

template<int SPLIT>
__global__ __launch_bounds__(256, 4) void attn32(
    const short* __restrict__ Q, const short* __restrict__ Kg,
    const short* __restrict__ Vt, short* __restrict__ Y,
    float* __restrict__ Op, float* __restrict__ ml){
  __shared__ short Ks[2][64 * 64];
  __shared__ short Vs[2][64 * 64];
  __shared__ float bounce[4][32];
  const int tid = threadIdx.x;
  const int w = tid >> 6, l = tid & 63;
  const int lq = l & 31, h = l >> 5;
  const int bx = blockIdx.x;
  int i, hf;
  if constexpr (SPLIT){
    int u = bx >> 5, v = u & 15;
    i = (v < 8) ? 15 - v : v - 8;
    hf = u >> 4;
  } else {
    i = (bx < 256) ? 15 - (bx >> 5) : (bx >> 5) - 8;
    hf = 0;
  }
  const int bh = bx & 31;
  const int q0 = i * 128, qw = q0 + w * 32;
  const int t0 = (SPLIT && hf) ? (i + 1) : 0;
  const int t1 = (SPLIT && !hf) ? (i + 1) : 2 * (i + 1);

  // Q fragments (B-operand): qb[dk] = Q[qw+lq][16*dk + 8*h .. +7]
  bf16x8 qb[4];
  {
    const short* qbase = Q + (bh * T_ + qw + lq) * HD_;
#pragma unroll
    for (int dk = 0; dk < 4; dk++)
      qb[dk] = *(const bf16x8*)(qbase + dk * 16 + h * 8);
  }

  f32x16 o0 = {}, o1 = {};
  float m = -1e30f, ll = 0.f;

  auto stage = [&](int buf, int t){
#pragma unroll
    for (int j = 0; j < 2; j++){
      int idx = j * 256 + tid;
      int row = idx >> 3, cb = (idx & 7) * 16;     // 128B rows
      int cbs = cb ^ ((row & 7) << 4);
      gl2lds16(Kg + (bh * T_ + t * 64 + row) * HD_ + (cbs >> 1), (char*)Ks[buf] + idx * 16);
      gl2lds16(Vt + (bh * HD_ + row) * T_ + t * 64 + (cbs >> 1), (char*)Vs[buf] + idx * 16);
    }
  };

  stage(0, t0);
  for (int t = t0; t < t1; ++t){
    const int cur = (t - t0) & 1;
    if (t + 1 < t1){
      stage(cur ^ 1, t + 1);                            // prefetch next tile
      asm volatile("s_waitcnt vmcnt(4)" ::: "memory");  // current tile landed
    } else {
      asm volatile("s_waitcnt vmcnt(0)" ::: "memory");
    }
    __builtin_amdgcn_s_barrier();
    __builtin_amdgcn_sched_barrier(0);

    const int kvb = t * 64;
    if (kvb <= qw + 31){                  // warp still below/on its diagonal
      const short* Kc = Ks[cur];
      const short* Vc = Vs[cur];

      // S^T = K . Q^T : s[kb] covers kv [kvb+32*kb, +32), q col = lq
      f32x16 s[2] = {};
      __builtin_amdgcn_s_setprio(1);
#pragma unroll
      for (int kb = 0; kb < 2; kb++){
        int row = kb * 32 + lq;
        const char* rp = (const char*)Kc + row * 128;
        int swz = (row & 7) << 4;
#pragma unroll
        for (int dk = 0; dk < 4; dk++){
          bf16x8 ka = *(const bf16x8*)(rp + ((dk * 32 + h * 16) ^ swz));
          s[kb] = __builtin_amdgcn_mfma_f32_32x32x16_bf16(ka, qb[dk], s[kb], 0, 0, 0);
        }
      }
      __builtin_amdgcn_s_setprio(0);

      const int qg = qw + lq;
      if (kvb + 63 > qw){                 // diagonal tile: causal mask
#pragma unroll
        for (int kb = 0; kb < 2; kb++)
#pragma unroll
          for (int r = 0; r < 16; r++){
            int kv = kvb + kb * 32 + crow(r, h);
            if (kv > qg) s[kb][r] = -1e30f;
          }
      }

      // row max: lane-local + 1 cross-half shuffle
      float pm = s[0][0];
#pragma unroll
      for (int r = 1; r < 16; r++) pm = fmaxf(pm, s[0][r]);
#pragma unroll
      for (int r = 0; r < 16; r++) pm = fmaxf(pm, s[1][r]);
      pm = fmaxf(pm, __shfl_xor(pm, 32));

      // defer-max (T13): rescale O only when max grew > 8 (log2 domain)
      if (__any(pm > m + 8.f)){
        float mn = fmaxf(pm, m);
        float sf = __builtin_amdgcn_exp2f(m - mn);
        m = mn;
        ll *= sf;
        bounce[w][lq] = sf;               // lanes l and l+32 write same value
#pragma unroll
        for (int r = 0; r < 16; r++){
          float sr = bounce[w][crow(r, h)];
          o0[r] *= sr; o1[r] *= sr;
        }
      }

      // P = 2^(s - m); row sum
      float ts = 0.f;
#pragma unroll
      for (int kb = 0; kb < 2; kb++)
#pragma unroll
        for (int r = 0; r < 16; r++){
          float p = __builtin_amdgcn_exp2f(s[kb][r] - m);
          s[kb][r] = p;
          ts += p;
        }
      ts += __shfl_xor(ts, 32);
      ll += ts;

      // pack P to bf16 pairs; pw0[kb*4+g] = kv kb*32+8g+4h'+{0,1}, pw1: +{2,3}
      unsigned pw0[8], pw1[8];
#pragma unroll
      for (int kb = 0; kb < 2; kb++)
#pragma unroll
        for (int gg = 0; gg < 4; gg++){
          unsigned r0, r1;
          asm("v_cvt_pk_bf16_f32 %0, %1, %2" : "=v"(r0) : "v"(s[kb][gg * 4 + 0]), "v"(s[kb][gg * 4 + 1]));
          asm("v_cvt_pk_bf16_f32 %0, %1, %2" : "=v"(r1) : "v"(s[kb][gg * 4 + 2]), "v"(s[kb][gg * 4 + 3]));
          pw0[kb * 4 + gg] = r0;
          pw1[kb * 4 + gg] = r1;
        }
      // swap(D=even, S=odd): D_hi <-> S_lo. even reg -> A-word0, odd -> A-word2.
#pragma unroll
      for (int ks = 0; ks < 4; ks++){
        asm("v_permlane32_swap_b32 %0, %1" : "+v"(pw0[2 * ks]), "+v"(pw0[2 * ks + 1]));
        asm("v_permlane32_swap_b32 %0, %1" : "+v"(pw1[2 * ks]), "+v"(pw1[2 * ks + 1]));
      }

      // O += P @ V
      __builtin_amdgcn_s_setprio(1);
#pragma unroll
      for (int ks = 0; ks < 4; ks++){
        uint4v paw;
        paw[0] = pw0[2 * ks];     paw[1] = pw1[2 * ks];
        paw[2] = pw0[2 * ks + 1]; paw[3] = pw1[2 * ks + 1];
        bf16x8 pa = __builtin_bit_cast(bf16x8, paw);
#pragma unroll
        for (int nb = 0; nb < 2; nb++){
          int row = nb * 32 + lq;
          bf16x8 vb = *(const bf16x8*)((const char*)Vc + row * 128 +
                        ((ks * 32 + h * 16) ^ ((row & 7) << 4)));
          if (nb == 0) o0 = __builtin_amdgcn_mfma_f32_32x32x16_bf16(pa, vb, o0, 0, 0, 0);
          else         o1 = __builtin_amdgcn_mfma_f32_32x32x16_bf16(pa, vb, o1, 0, 0, 0);
        }
      }
      __builtin_amdgcn_s_setprio(0);
    }
    __builtin_amdgcn_sched_barrier(0);
    __builtin_amdgcn_s_barrier();        // all reads of buf[cur] done
  }

  if constexpr (SPLIT){
    // store unnormalized partials (f32) + per-row (m, l)
    float* Oq = Op + ((size_t)(hf * 32 + bh)) * (size_t)T_ * 64;
    if (h == 0){
      float* mlr = ml + ((size_t)(hf * 32 + bh) * T_ + (qw + lq)) * 2;
      mlr[0] = m; mlr[1] = ll;
    }
#pragma unroll
    for (int r = 0; r < 16; r++){
      int qg = qw + crow(r, h);
      Oq[qg * 64 + lq]      = o0[r];
      Oq[qg * 64 + 32 + lq] = o1[r];
    }
  } else {
    // normalize by 1/l (broadcast via warp-private LDS) and store
    bounce[w][lq] = __builtin_amdgcn_rcpf(ll);
    const int b = bh >> 4, hh = bh & 15;
#pragma unroll
    for (int r = 0; r < 16; r++){
      int row = crow(r, h);
      float rl = bounce[w][row];
      int qg = qw + row;
      short* yb = Y + (b * T_ + qg) * D_ + hh * 64;
      yb[lq]      = f2bf(o0[r] * rl);
      yb[32 + lq] = f2bf(o1[r] * rl);
    }
  }
}

// ---------------- merge the two kv-split halves ----------------
// Op: f32 [2][32][2048][64]; ml: f32 [2][32][2048][2]; Y: bf16 [B,T,1024].
// Thread: rid = bh*2048+t, 16 cols.  262144 threads.
__global__ __launch_bounds__(256) void attn_merge(
    const float* __restrict__ Op, const float* __restrict__ ml,
    short* __restrict__ Y){
  int gid = blockIdx.x * 256 + threadIdx.x;
  int rid = gid >> 2, c16 = (gid & 3) * 16;
  float m1 = ml[rid * 2],           l1 = ml[rid * 2 + 1];
  float m2 = ml[131072 + rid * 2],  l2 = ml[131072 + rid * 2 + 1];
  float M  = fmaxf(m1, m2);
  float f1 = __builtin_amdgcn_exp2f(m1 - M);
  float f2 = __builtin_amdgcn_exp2f(m2 - M);
  float rl = 1.f / (f1 * l1 + f2 * l2);
  f1 *= rl; f2 *= rl;
  const float4* O1 = (const float4*)(Op + (size_t)rid * 64 + c16);
  const float4* O2 = (const float4*)(Op + 4194304ull + (size_t)rid * 64 + c16);
  int bh = rid >> 11, t = rid & 2047;
  short* yb = Y + (((bh >> 4) * T_ + t) * D_) + (bh & 15) * 64 + c16;
#pragma unroll
  for (int j = 0; j < 4; j++){
    float4 a = O1[j], b = O2[j];
    short4v o;
    o[0] = f2bf(f1 * a.x + f2 * b.x);
    o[1] = f2bf(f1 * a.y + f2 * b.y);
    o[2] = f2bf(f1 * a.z + f2 * b.z);
    o[3] = f2bf(f1 * a.w + f2 * b.w);
    *(short4v*)(yb + j * 4) = o;
  }
}

// ---------------- launch ----------------
extern "C" void kernel_launch(void* const* d_in, const int* in_sizes, int n_in,
                              void* d_out, int out_size, void* d_ws, size_t ws_size,
                              hipStream_t stream) {
  const float* x  = (const float*)d_in[0];
  const float* W1 = (const float*)d_in[1];
  const float* b1 = (const float*)d_in[2];
  const float* W2 = (const float*)d_in[3];
  const float* b2 = (const float*)d_in[4];
  float* out = (float*)d_out;

  char* ws = (char*)d_ws;
  short* W1T = (short*)(ws);                         // [3072][1024] bf16, 6 MB
  short* W2T = (short*)(ws + 6291456);               // [1024][1024] bf16, 2 MB
  short* xb  = (short*)(ws + 8388608);               // [4096][1024] bf16, 8 MB
  short* q   = (short*)(ws + 16777216);              // [B,H,T,64]  bf16, 8 MB
  short* kk  = (short*)(ws + 25165824);              // [B,H,T,64]  bf16, 8 MB
  short* vT  = (short*)(ws + 33554432);              // [B,H,64,T]  bf16, 8 MB
  float* Op  = (float*)(ws + 41943040);              // [2][32][2048][64] f32, 32 MB
  float* mlb = (float*)(ws + 41943040 + 33554432);   // [2][32][2048][2]  f32, 1 MB
  short* y   = xb;                                   // alias: xb dead after QKV GEMM

  const size_t need = 41943040ull + 33554432ull + 1048576ull;
  const bool split = ws_size >= need;

  convert_f32_bf16<<<dim3(4096), dim3(256), 0, stream>>>(x, xb);
  transpose_f32_bf16<<<dim3(96, 32), dim3(256), 0, stream>>>(W1, W1T, 1024, 3072);
  transpose_f32_bf16<<<dim3(32, 32), dim3(256), 0, stream>>>(W2, W2T, 1024, 1024);
  gemm_bt<3072, 1024, 0><<<dim3(24, 32), dim3(256), 0, stream>>>(xb, W1T, b1, q, kk, vT, nullptr);
  if (split){
    attn32<1><<<dim3(1024), dim3(256), 0, stream>>>(q, kk, vT, nullptr, Op, mlb);
    attn_merge<<<dim3(1024), dim3(256), 0, stream>>>(Op, mlb, y);
  } else {
    attn32<0><<<dim3(512), dim3(256), 0, stream>>>(q, kk, vT, y, nullptr, nullptr);
  }
  gemm_bt<1024, 1024, 1><<<dim3(8, 32), dim3(256), 0, stream>>>(y, W2T, b2, nullptr, nullptr, nullptr, out);
}

// Round 8
// 117.833 us; speedup vs baseline: 1.1918x; 1.0473x over previous
//
#include <hip/hip_runtime.h>

typedef __attribute__((ext_vector_type(8))) short bf16x8;
typedef __attribute__((ext_vector_type(4))) float f32x4;
typedef __attribute__((ext_vector_type(16))) float f32x16;
typedef __attribute__((ext_vector_type(4))) short short4v;
typedef __attribute__((ext_vector_type(4))) unsigned int uint4v;

#define B_  2
#define T_  2048
#define D_  1024
#define H_  16
#define HD_ 64

__device__ inline short f2bf(float f){
  unsigned u = __builtin_bit_cast(unsigned, f);
  u += 0x7fff + ((u >> 16) & 1);          // round-to-nearest-even
  return (short)(u >> 16);
}

__device__ inline void gl2lds16(const void* g, void* l){
  __builtin_amdgcn_global_load_lds(
      (const __attribute__((address_space(1))) unsigned int*)g,
      (__attribute__((address_space(3))) unsigned int*)l, 16, 0, 0);
}

// ---------------- fused prep: x->bf16, W1->W1T bf16, W2->W2T bf16 ----------
__device__ inline void transpose_tile(const float* __restrict__ in,
                                      short* __restrict__ out,
                                      int R, int C, int bx, int by){
  __shared__ float tile[32][33];
  int tx = threadIdx.x & 31, ty0 = threadIdx.x >> 5;
#pragma unroll
  for (int i = 0; i < 4; i++){
    int ty = ty0 + i * 8;
    tile[ty][tx] = in[(by + ty) * C + bx + tx];
  }
  __syncthreads();
#pragma unroll
  for (int i = 0; i < 4; i++){
    int ty = ty0 + i * 8;
    out[(bx + ty) * R + by + tx] = f2bf(tile[tx][ty]);
  }
}

__global__ __launch_bounds__(256) void prep(
    const float* __restrict__ x,  short* __restrict__ xb,
    const float* __restrict__ W1, short* __restrict__ W1T,
    const float* __restrict__ W2, short* __restrict__ W2T){
  const int bid = blockIdx.x;
  if (bid < 4096){
    int i = (bid * 256 + threadIdx.x) * 4;
    float4 v = *(const float4*)(x + i);
    short4v o;
    o[0] = f2bf(v.x); o[1] = f2bf(v.y); o[2] = f2bf(v.z); o[3] = f2bf(v.w);
    *(short4v*)(xb + i) = o;
  } else if (bid < 4096 + 3072){
    int tb = bid - 4096;                       // W1 [1024][3072] -> W1T
    transpose_tile(W1, W1T, 1024, 3072, (tb % 96) << 5, (tb / 96) << 5);
  } else {
    int tb = bid - 7168;                       // W2 [1024][1024] -> W2T
    transpose_tile(W2, W2T, 1024, 1024, (tb % 32) << 5, (tb / 32) << 5);
  }
}

// ---------------- GEMM: C = A[M][K] @ Bt[N][K]^T + bias ----------------
// 2-phase double-buffered pipeline, raw barriers, counted vmcnt (T3+T4).
// BM=128 fixed; BN_/TPB templated: QKV uses 128x256 w/ 8 waves (2x4 wave grid,
// A-frags shared 4x -> LDS bytes/FLOP 45.7 -> 21 B/KF); proj stays 128x128.
#define BM 128
#define BK 32

// Q pre-scale: 1/sqrt(64) * log2(e)  (softmax runs in exp2 domain)
#define QSCALE 0.18033688011112042f

template<int N_, int K_, int EPI, int BN_, int TPB>
__global__ __launch_bounds__(TPB, 4) void gemm_bt(
    const short* __restrict__ A, const short* __restrict__ Bt,
    const float* __restrict__ bias,
    short* __restrict__ q, short* __restrict__ kk, short* __restrict__ vT,
    float* __restrict__ outf){
  constexpr int NWX = BN_ / 64;              // waves along N
  constexpr int LA  = (BM * 64) / (TPB * 16);   // gl2lds per thread for A
  constexpr int LB  = (BN_ * 64) / (TPB * 16);  // gl2lds per thread for B
  __shared__ short As[2][BM * BK];
  __shared__ short Bs[2][BN_ * BK];
  const int tid = threadIdx.x;
  const int lane = tid & 63, w = tid >> 6;
  const int wm = w / NWX, wn = w % NWX;
  const int lr = lane & 15, lk = lane >> 4;
  const int brow = blockIdx.y * BM, bcol = blockIdx.x * BN_;
  f32x4 acc[4][4] = {};
  const short* Ag = A  + brow * K_;
  const short* Bg = Bt + bcol * K_;

  auto stage = [&](int buf, int k0){
#pragma unroll
    for (int i = 0; i < LA; i++){
      int idx = i * TPB + tid;
      int row = idx >> 2, c8 = (idx & 3) * 8;   // 64B rows of 32 bf16
      gl2lds16(Ag + row * K_ + k0 + c8, (char*)As[buf] + idx * 16);
    }
#pragma unroll
    for (int i = 0; i < LB; i++){
      int idx = i * TPB + tid;
      int row = idx >> 2, c8 = (idx & 3) * 8;
      gl2lds16(Bg + row * K_ + k0 + c8, (char*)Bs[buf] + idx * 16);
    }
  };

  const int NT = K_ / BK;
  stage(0, 0);
  for (int t = 0; t < NT; ++t){
    const int cur = t & 1;
    if (t + 1 < NT){
      stage(cur ^ 1, (t + 1) * BK);                    // prefetch next K-tile
      if constexpr (LA + LB == 3)
        asm volatile("s_waitcnt vmcnt(3)" ::: "memory");
      else
        asm volatile("s_waitcnt vmcnt(4)" ::: "memory");
    } else {
      asm volatile("s_waitcnt vmcnt(0)" ::: "memory");
    }
    __builtin_amdgcn_s_barrier();                      // buf[cur] fully staged
    __builtin_amdgcn_sched_barrier(0);

    bf16x8 a[4], b[4];
#pragma unroll
    for (int mf = 0; mf < 4; mf++)
      a[mf] = *(const bf16x8*)(As[cur] + (wm * 64 + mf * 16 + lr) * BK + lk * 8);
#pragma unroll
    for (int nf = 0; nf < 4; nf++)
      b[nf] = *(const bf16x8*)(Bs[cur] + (wn * 64 + nf * 16 + lr) * BK + lk * 8);
    __builtin_amdgcn_s_setprio(1);
#pragma unroll
    for (int mf = 0; mf < 4; mf++)
#pragma unroll
      for (int nf = 0; nf < 4; nf++)
        acc[mf][nf] = __builtin_amdgcn_mfma_f32_16x16x32_bf16(a[mf], b[nf], acc[mf][nf], 0, 0, 0);
    __builtin_amdgcn_s_setprio(0);
    __builtin_amdgcn_sched_barrier(0);
    __builtin_amdgcn_s_barrier();                      // reads of buf[cur] done
  }

  if constexpr (EPI == 0){
    // C/D layout: col = lane&15, row = (lane>>4)*4 + r
#pragma unroll
    for (int nf = 0; nf < 4; nf++){
      int n = bcol + wn * 64 + nf * 16 + lr;
      float bv = bias[n];
      int sec = n >> 10, d = n & 1023, h = d >> 6, hd = d & 63;
#pragma unroll
      for (int mf = 0; mf < 4; mf++){
        int m0 = brow + wm * 64 + mf * 16 + lk * 4;
        int b = m0 >> 11, t0 = m0 & 2047;
        int bh = b * H_ + h;
        if (sec == 0){
#pragma unroll
          for (int r = 0; r < 4; r++)
            q[(bh * T_ + t0 + r) * HD_ + hd] = f2bf((acc[mf][nf][r] + bv) * QSCALE);
        } else if (sec == 1){
#pragma unroll
          for (int r = 0; r < 4; r++)
            kk[(bh * T_ + t0 + r) * HD_ + hd] = f2bf(acc[mf][nf][r] + bv);
        } else {
          float v0 = acc[mf][nf][0] + bv, v1 = acc[mf][nf][1] + bv;
          float v2 = acc[mf][nf][2] + bv, v3 = acc[mf][nf][3] + bv;
          unsigned lo = (unsigned)(unsigned short)f2bf(v0) | ((unsigned)(unsigned short)f2bf(v1) << 16);
          unsigned hi = (unsigned)(unsigned short)f2bf(v2) | ((unsigned)(unsigned short)f2bf(v3) << 16);
          uint2 pk; pk.x = lo; pk.y = hi;
          *(uint2*)(vT + (bh * HD_ + hd) * T_ + t0) = pk;   // v stored transposed [B,H,hd,T]
        }
      }
    }
  } else {
#pragma unroll
    for (int nf = 0; nf < 4; nf++){
      int n = bcol + wn * 64 + nf * 16 + lr;
      float bv = bias[n];
#pragma unroll
      for (int mf = 0; mf < 4; mf++){
        int m0 = brow + wm * 64 + mf * 16 + lk * 4;
#pragma unroll
        for (int r = 0; r < 4; r++)
          outf[(m0 + r) * N_ + n] = acc[mf][nf][r] + bv;
      }
    }
  }
}

// ---------------- causal flash attention, 32x32 swapped-QK^T ----------------
// Q,K: [B*H, T, 64] bf16 (Q pre-scaled by QSCALE => logits in exp2 domain)
// Vt: [B*H, 64, T] bf16.
// SPLIT=1: grid 1024, kv range split in two halves with private online-softmax
//   state; writes unnormalized f32 partials Op + (m,l); merged by attn_merge.
__device__ inline int crow(int r, int h){ return (r & 3) + 8 * (r >> 2) + 4 * h; }

template<int SPLIT>
__global__ __launch_bounds__(256, 4) void attn32(
    const short* __restrict__ Q, const short* __restrict__ Kg,
    const short* __restrict__ Vt, short* __restrict__ Y,
    float* __restrict__ Op, float* __restrict__ ml){
  __shared__ short Ks[2][64 * 64];
  __shared__ short Vs[2][64 * 64];
  __shared__ float bounce[4][32];
  const int tid = threadIdx.x;
  const int w = tid >> 6, l = tid & 63;
  const int lq = l & 31, h = l >> 5;
  const int bx = blockIdx.x;
  int i, hf;
  if constexpr (SPLIT){
    int u = bx >> 5, v = u & 15;
    i = (v < 8) ? 15 - v : v - 8;
    hf = u >> 4;
  } else {
    i = (bx < 256) ? 15 - (bx >> 5) : (bx >> 5) - 8;
    hf = 0;
  }
  const int bh = bx & 31;
  const int q0 = i * 128, qw = q0 + w * 32;
  const int t0 = (SPLIT && hf) ? (i + 1) : 0;
  const int t1 = (SPLIT && !hf) ? (i + 1) : 2 * (i + 1);

  // Q fragments (B-operand): qb[dk] = Q[qw+lq][16*dk + 8*h .. +7]
  bf16x8 qb[4];
  {
    const short* qbase = Q + (bh * T_ + qw + lq) * HD_;
#pragma unroll
    for (int dk = 0; dk < 4; dk++)
      qb[dk] = *(const bf16x8*)(qbase + dk * 16 + h * 8);
  }

  f32x16 o0 = {}, o1 = {};
  float m = -1e30f, ll = 0.f;

  auto stage = [&](int buf, int t){
#pragma unroll
    for (int j = 0; j < 2; j++){
      int idx = j * 256 + tid;
      int row = idx >> 3, cb = (idx & 7) * 16;     // 128B rows
      int cbs = cb ^ ((row & 7) << 4);
      gl2lds16(Kg + (bh * T_ + t * 64 + row) * HD_ + (cbs >> 1), (char*)Ks[buf] + idx * 16);
      gl2lds16(Vt + (bh * HD_ + row) * T_ + t * 64 + (cbs >> 1), (char*)Vs[buf] + idx * 16);
    }
  };

  stage(0, t0);
  for (int t = t0; t < t1; ++t){
    const int cur = (t - t0) & 1;
    if (t + 1 < t1){
      stage(cur ^ 1, t + 1);                            // prefetch next tile
      asm volatile("s_waitcnt vmcnt(4)" ::: "memory");  // current tile landed
    } else {
      asm volatile("s_waitcnt vmcnt(0)" ::: "memory");
    }
    __builtin_amdgcn_s_barrier();
    __builtin_amdgcn_sched_barrier(0);

    const int kvb = t * 64;
    if (kvb <= qw + 31){                  // warp still below/on its diagonal
      const short* Kc = Ks[cur];
      const short* Vc = Vs[cur];

      // S^T = K . Q^T : s[kb] covers kv [kvb+32*kb, +32), q col = lq
      f32x16 s[2] = {};
      __builtin_amdgcn_s_setprio(1);
#pragma unroll
      for (int kb = 0; kb < 2; kb++){
        int row = kb * 32 + lq;
        const char* rp = (const char*)Kc + row * 128;
        int swz = (row & 7) << 4;
#pragma unroll
        for (int dk = 0; dk < 4; dk++){
          bf16x8 ka = *(const bf16x8*)(rp + ((dk * 32 + h * 16) ^ swz));
          s[kb] = __builtin_amdgcn_mfma_f32_32x32x16_bf16(ka, qb[dk], s[kb], 0, 0, 0);
        }
      }
      __builtin_amdgcn_s_setprio(0);

      const int qg = qw + lq;
      if (kvb + 63 > qw){                 // diagonal tile: causal mask
#pragma unroll
        for (int kb = 0; kb < 2; kb++)
#pragma unroll
          for (int r = 0; r < 16; r++){
            int kv = kvb + kb * 32 + crow(r, h);
            if (kv > qg) s[kb][r] = -1e30f;
          }
      }

      // row max: lane-local + 1 cross-half shuffle
      float pm = s[0][0];
#pragma unroll
      for (int r = 1; r < 16; r++) pm = fmaxf(pm, s[0][r]);
#pragma unroll
      for (int r = 0; r < 16; r++) pm = fmaxf(pm, s[1][r]);
      pm = fmaxf(pm, __shfl_xor(pm, 32));

      // defer-max (T13): rescale O only when max grew > 8 (log2 domain)
      if (__any(pm > m + 8.f)){
        float mn = fmaxf(pm, m);
        float sf = __builtin_amdgcn_exp2f(m - mn);
        m = mn;
        ll *= sf;
        bounce[w][lq] = sf;               // lanes l and l+32 write same value
#pragma unroll
        for (int r = 0; r < 16; r++){
          float sr = bounce[w][crow(r, h)];
          o0[r] *= sr; o1[r] *= sr;
        }
      }

      // P = 2^(s - m); row sum
      float ts = 0.f;
#pragma unroll
      for (int kb = 0; kb < 2; kb++)
#pragma unroll
        for (int r = 0; r < 16; r++){
          float p = __builtin_amdgcn_exp2f(s[kb][r] - m);
          s[kb][r] = p;
          ts += p;
        }
      ts += __shfl_xor(ts, 32);
      ll += ts;

      // pack P to bf16 pairs; pw0[kb*4+g] = kv kb*32+8g+4h'+{0,1}, pw1: +{2,3}
      unsigned pw0[8], pw1[8];
#pragma unroll
      for (int kb = 0; kb < 2; kb++)
#pragma unroll
        for (int gg = 0; gg < 4; gg++){
          unsigned r0, r1;
          asm("v_cvt_pk_bf16_f32 %0, %1, %2" : "=v"(r0) : "v"(s[kb][gg * 4 + 0]), "v"(s[kb][gg * 4 + 1]));
          asm("v_cvt_pk_bf16_f32 %0, %1, %2" : "=v"(r1) : "v"(s[kb][gg * 4 + 2]), "v"(s[kb][gg * 4 + 3]));
          pw0[kb * 4 + gg] = r0;
          pw1[kb * 4 + gg] = r1;
        }
      // swap(D=even, S=odd): D_hi <-> S_lo. even reg -> A-word0, odd -> A-word2.
#pragma unroll
      for (int ks = 0; ks < 4; ks++){
        asm("v_permlane32_swap_b32 %0, %1" : "+v"(pw0[2 * ks]), "+v"(pw0[2 * ks + 1]));
        asm("v_permlane32_swap_b32 %0, %1" : "+v"(pw1[2 * ks]), "+v"(pw1[2 * ks + 1]));
      }

      // O += P @ V
      __builtin_amdgcn_s_setprio(1);
#pragma unroll
      for (int ks = 0; ks < 4; ks++){
        uint4v paw;
        paw[0] = pw0[2 * ks];     paw[1] = pw1[2 * ks];
        paw[2] = pw0[2 * ks + 1]; paw[3] = pw1[2 * ks + 1];
        bf16x8 pa = __builtin_bit_cast(bf16x8, paw);
#pragma unroll
        for (int nb = 0; nb < 2; nb++){
          int row = nb * 32 + lq;
          bf16x8 vb = *(const bf16x8*)((const char*)Vc + row * 128 +
                        ((ks * 32 + h * 16) ^ ((row & 7) << 4)));
          if (nb == 0) o0 = __builtin_amdgcn_mfma_f32_32x32x16_bf16(pa, vb, o0, 0, 0, 0);
          else         o1 = __builtin_amdgcn_mfma_f32_32x32x16_bf16(pa, vb, o1, 0, 0, 0);
        }
      }
      __builtin_amdgcn_s_setprio(0);
    }
    __builtin_amdgcn_sched_barrier(0);
    __builtin_amdgcn_s_barrier();        // all reads of buf[cur] done
  }

  if constexpr (SPLIT){
    // store unnormalized partials (f32) + per-row (m, l)
    float* Oq = Op + ((size_t)(hf * 32 + bh)) * (size_t)T_ * 64;
    if (h == 0){
      float* mlr = ml + ((size_t)(hf * 32 + bh) * T_ + (qw + lq)) * 2;
      mlr[0] = m; mlr[1] = ll;
    }
#pragma unroll
    for (int r = 0; r < 16; r++){
      int qg = qw + crow(r, h);
      Oq[qg * 64 + lq]      = o0[r];
      Oq[qg * 64 + 32 + lq] = o1[r];
    }
  } else {
    // normalize by 1/l (broadcast via warp-private LDS) and store
    bounce[w][lq] = __builtin_amdgcn_rcpf(ll);
    const int b = bh >> 4, hh = bh & 15;
#pragma unroll
    for (int r = 0; r < 16; r++){
      int row = crow(r, h);
      float rl = bounce[w][row];
      int qg = qw + row;
      short* yb = Y + (b * T_ + qg) * D_ + hh * 64;
      yb[lq]      = f2bf(o0[r] * rl);
      yb[32 + lq] = f2bf(o1[r] * rl);
    }
  }
}

// ---------------- merge the two kv-split halves ----------------
__global__ __launch_bounds__(256) void attn_merge(
    const float* __restrict__ Op, const float* __restrict__ ml,
    short* __restrict__ Y){
  int gid = blockIdx.x * 256 + threadIdx.x;
  int rid = gid >> 2, c16 = (gid & 3) * 16;
  float m1 = ml[rid * 2],           l1 = ml[rid * 2 + 1];
  float m2 = ml[131072 + rid * 2],  l2 = ml[131072 + rid * 2 + 1];
  float M  = fmaxf(m1, m2);
  float f1 = __builtin_amdgcn_exp2f(m1 - M);
  float f2 = __builtin_amdgcn_exp2f(m2 - M);
  float rl = 1.f / (f1 * l1 + f2 * l2);
  f1 *= rl; f2 *= rl;
  const float4* O1 = (const float4*)(Op + (size_t)rid * 64 + c16);
  const float4* O2 = (const float4*)(Op + 4194304ull + (size_t)rid * 64 + c16);
  int bh = rid >> 11, t = rid & 2047;
  short* yb = Y + (((bh >> 4) * T_ + t) * D_) + (bh & 15) * 64 + c16;
#pragma unroll
  for (int j = 0; j < 4; j++){
    float4 a = O1[j], b = O2[j];
    short4v o;
    o[0] = f2bf(f1 * a.x + f2 * b.x);
    o[1] = f2bf(f1 * a.y + f2 * b.y);
    o[2] = f2bf(f1 * a.z + f2 * b.z);
    o[3] = f2bf(f1 * a.w + f2 * b.w);
    *(short4v*)(yb + j * 4) = o;
  }
}

// ---------------- launch ----------------
extern "C" void kernel_launch(void* const* d_in, const int* in_sizes, int n_in,
                              void* d_out, int out_size, void* d_ws, size_t ws_size,
                              hipStream_t stream) {
  const float* x  = (const float*)d_in[0];
  const float* W1 = (const float*)d_in[1];
  const float* b1 = (const float*)d_in[2];
  const float* W2 = (const float*)d_in[3];
  const float* b2 = (const float*)d_in[4];
  float* out = (float*)d_out;

  char* ws = (char*)d_ws;
  short* W1T = (short*)(ws);                         // [3072][1024] bf16, 6 MB
  short* W2T = (short*)(ws + 6291456);               // [1024][1024] bf16, 2 MB
  short* xb  = (short*)(ws + 8388608);               // [4096][1024] bf16, 8 MB
  short* q   = (short*)(ws + 16777216);              // [B,H,T,64]  bf16, 8 MB
  short* kk  = (short*)(ws + 25165824);              // [B,H,T,64]  bf16, 8 MB
  short* vT  = (short*)(ws + 33554432);              // [B,H,64,T]  bf16, 8 MB
  float* Op  = (float*)(ws + 41943040);              // [2][32][2048][64] f32, 32 MB
  float* mlb = (float*)(ws + 41943040 + 33554432);   // [2][32][2048][2]  f32, 1 MB
  short* y   = xb;                                   // alias: xb dead after QKV GEMM

  const size_t need = 41943040ull + 33554432ull + 1048576ull;
  const bool split = ws_size >= need;

  prep<<<dim3(8192), dim3(256), 0, stream>>>(x, xb, W1, W1T, W2, W2T);
  gemm_bt<3072, 1024, 0, 256, 512><<<dim3(12, 32), dim3(512), 0, stream>>>(xb, W1T, b1, q, kk, vT, nullptr);
  if (split){
    attn32<1><<<dim3(1024), dim3(256), 0, stream>>>(q, kk, vT, nullptr, Op, mlb);
    attn_merge<<<dim3(1024), dim3(256), 0, stream>>>(Op, mlb, y);
  } else {
    attn32<0><<<dim3(512), dim3(256), 0, stream>>>(q, kk, vT, y, nullptr, nullptr);
  }
  gemm_bt<1024, 1024, 1, 128, 256><<<dim3(8, 32), dim3(256), 0, stream>>>(y, W2T, b2, nullptr, nullptr, nullptr, out);
}

// Round 9
// 116.235 us; speedup vs baseline: 1.2081x; 1.0137x over previous
//
#include <hip/hip_runtime.h>

typedef __attribute__((ext_vector_type(8))) short bf16x8;
typedef __attribute__((ext_vector_type(4))) float f32x4;
typedef __attribute__((ext_vector_type(16))) float f32x16;
typedef __attribute__((ext_vector_type(4))) short short4v;
typedef __attribute__((ext_vector_type(4))) unsigned int uint4v;

#define B_  2
#define T_  2048
#define D_  1024
#define H_  16
#define HD_ 64

__device__ inline short f2bf(float f){
  unsigned u = __builtin_bit_cast(unsigned, f);
  u += 0x7fff + ((u >> 16) & 1);          // round-to-nearest-even
  return (short)(u >> 16);
}

__device__ inline void gl2lds16(const void* g, void* l){
  __builtin_amdgcn_global_load_lds(
      (const __attribute__((address_space(1))) unsigned int*)g,
      (__attribute__((address_space(3))) unsigned int*)l, 16, 0, 0);
}

// ---------------- fused prep: x->bf16, W1->W1T bf16, W2->W2T bf16 ----------
__device__ inline void transpose_tile(const float* __restrict__ in,
                                      short* __restrict__ out,
                                      int R, int C, int bx, int by){
  __shared__ float tile[32][33];
  int tx = threadIdx.x & 31, ty0 = threadIdx.x >> 5;
#pragma unroll
  for (int i = 0; i < 4; i++){
    int ty = ty0 + i * 8;
    tile[ty][tx] = in[(by + ty) * C + bx + tx];
  }
  __syncthreads();
#pragma unroll
  for (int i = 0; i < 4; i++){
    int ty = ty0 + i * 8;
    out[(bx + ty) * R + by + tx] = f2bf(tile[tx][ty]);
  }
}

__global__ __launch_bounds__(256) void prep(
    const float* __restrict__ x,  short* __restrict__ xb,
    const float* __restrict__ W1, short* __restrict__ W1T,
    const float* __restrict__ W2, short* __restrict__ W2T){
  const int bid = blockIdx.x;
  if (bid < 4096){
    int i = (bid * 256 + threadIdx.x) * 4;
    float4 v = *(const float4*)(x + i);
    short4v o;
    o[0] = f2bf(v.x); o[1] = f2bf(v.y); o[2] = f2bf(v.z); o[3] = f2bf(v.w);
    *(short4v*)(xb + i) = o;
  } else if (bid < 4096 + 3072){
    int tb = bid - 4096;                       // W1 [1024][3072] -> W1T
    transpose_tile(W1, W1T, 1024, 3072, (tb % 96) << 5, (tb / 96) << 5);
  } else {
    int tb = bid - 7168;                       // W2 [1024][1024] -> W2T
    transpose_tile(W2, W2T, 1024, 1024, (tb % 32) << 5, (tb / 32) << 5);
  }
}

// ---------------- GEMM: C = A[M][K] @ Bt[N][K]^T + bias ----------------
// 3-buffer LDS, ONE barrier per K-iter: vmcnt(own) -> barrier -> stage(t+2)
// -> compute (no end barrier => waves de-lockstep; 2-iter prefetch slack).
#define BM 128
#define BN 128
#define BK 32

// Q pre-scale: 1/sqrt(64) * log2(e)  (softmax runs in exp2 domain)
#define QSCALE 0.18033688011112042f

template<int N_, int K_, int EPI>
__global__ __launch_bounds__(256, 3) void gemm_bt(
    const short* __restrict__ A, const short* __restrict__ Bt,
    const float* __restrict__ bias,
    short* __restrict__ q, short* __restrict__ kk, short* __restrict__ vT,
    float* __restrict__ outf){
  __shared__ short As[3][BM * BK];
  __shared__ short Bs[3][BN * BK];
  const int tid = threadIdx.x;
  const int lane = tid & 63, w = tid >> 6;
  const int wm = w >> 1, wn = w & 1;
  const int lr = lane & 15, lk = lane >> 4;
  const int brow = blockIdx.y * BM, bcol = blockIdx.x * BN;
  f32x4 acc[4][4] = {};
  const short* Ag = A  + brow * K_;
  const short* Bg = Bt + bcol * K_;

  auto stage = [&](int buf, int k0){
#pragma unroll
    for (int i = 0; i < 2; i++){
      int idx = i * 256 + tid;
      int row = idx >> 2, c8 = (idx & 3) * 8;   // 64B rows of 32 bf16
      gl2lds16(Ag + row * K_ + k0 + c8, (char*)As[buf] + idx * 16);
      gl2lds16(Bg + row * K_ + k0 + c8, (char*)Bs[buf] + idx * 16);
    }
  };

  const int NT = K_ / BK;
  stage(0, 0);
  stage(1, BK);
  for (int t = 0; t < NT; ++t){
    if (t + 1 < NT)
      asm volatile("s_waitcnt vmcnt(4)" ::: "memory");  // tile t landed (mine)
    else
      asm volatile("s_waitcnt vmcnt(0)" ::: "memory");
    __builtin_amdgcn_s_barrier();      // all waves: tile t landed, iter t-1 reads done
    __builtin_amdgcn_sched_barrier(0);
    if (t + 2 < NT)
      stage((t + 2) % 3, (t + 2) * BK);        // safe: buf last read at t-1
    __builtin_amdgcn_sched_barrier(0);

    const short* Ac = As[t % 3];
    const short* Bc = Bs[t % 3];
    bf16x8 a[4], b[4];
#pragma unroll
    for (int mf = 0; mf < 4; mf++)
      a[mf] = *(const bf16x8*)(Ac + (wm * 64 + mf * 16 + lr) * BK + lk * 8);
#pragma unroll
    for (int nf = 0; nf < 4; nf++)
      b[nf] = *(const bf16x8*)(Bc + (wn * 64 + nf * 16 + lr) * BK + lk * 8);
    __builtin_amdgcn_s_setprio(1);
#pragma unroll
    for (int mf = 0; mf < 4; mf++)
#pragma unroll
      for (int nf = 0; nf < 4; nf++)
        acc[mf][nf] = __builtin_amdgcn_mfma_f32_16x16x32_bf16(a[mf], b[nf], acc[mf][nf], 0, 0, 0);
    __builtin_amdgcn_s_setprio(0);
    // no end barrier: next iter's top barrier separates reads from restage
  }

  if constexpr (EPI == 0){
    // C/D layout: col = lane&15, row = (lane>>4)*4 + r
#pragma unroll
    for (int nf = 0; nf < 4; nf++){
      int n = bcol + wn * 64 + nf * 16 + lr;
      float bv = bias[n];
      int sec = n >> 10, d = n & 1023, h = d >> 6, hd = d & 63;
#pragma unroll
      for (int mf = 0; mf < 4; mf++){
        int m0 = brow + wm * 64 + mf * 16 + lk * 4;
        int b = m0 >> 11, t0 = m0 & 2047;
        int bh = b * H_ + h;
        if (sec == 0){
#pragma unroll
          for (int r = 0; r < 4; r++)
            q[(bh * T_ + t0 + r) * HD_ + hd] = f2bf((acc[mf][nf][r] + bv) * QSCALE);
        } else if (sec == 1){
#pragma unroll
          for (int r = 0; r < 4; r++)
            kk[(bh * T_ + t0 + r) * HD_ + hd] = f2bf(acc[mf][nf][r] + bv);
        } else {
          float v0 = acc[mf][nf][0] + bv, v1 = acc[mf][nf][1] + bv;
          float v2 = acc[mf][nf][2] + bv, v3 = acc[mf][nf][3] + bv;
          unsigned lo = (unsigned)(unsigned short)f2bf(v0) | ((unsigned)(unsigned short)f2bf(v1) << 16);
          unsigned hi = (unsigned)(unsigned short)f2bf(v2) | ((unsigned)(unsigned short)f2bf(v3) << 16);
          uint2 pk; pk.x = lo; pk.y = hi;
          *(uint2*)(vT + (bh * HD_ + hd) * T_ + t0) = pk;   // v stored transposed [B,H,hd,T]
        }
      }
    }
  } else {
#pragma unroll
    for (int nf = 0; nf < 4; nf++){
      int n = bcol + wn * 64 + nf * 16 + lr;
      float bv = bias[n];
#pragma unroll
      for (int mf = 0; mf < 4; mf++){
        int m0 = brow + wm * 64 + mf * 16 + lk * 4;
#pragma unroll
        for (int r = 0; r < 4; r++)
          outf[(m0 + r) * N_ + n] = acc[mf][nf][r] + bv;
      }
    }
  }
}

// ---------------- causal flash attention, 32x32 swapped-QK^T ----------------
// Q,K: [B*H, T, 64] bf16 (Q pre-scaled by QSCALE => logits in exp2 domain)
// Vt: [B*H, 64, T] bf16.
// SPLIT=1: grid 1024, kv range split in two halves with private online-softmax
//   state; writes unnormalized f32 partials Op + (m,l); merged by attn_merge.
__device__ inline int crow(int r, int h){ return (r & 3) + 8 * (r >> 2) + 4 * h; }

template<int SPLIT>
__global__ __launch_bounds__(256, 4) void attn32(
    const short* __restrict__ Q, const short* __restrict__ Kg,
    const short* __restrict__ Vt, short* __restrict__ Y,
    float* __restrict__ Op, float* __restrict__ ml){
  __shared__ short Ks[2][64 * 64];
  __shared__ short Vs[2][64 * 64];
  __shared__ float bounce[4][32];
  const int tid = threadIdx.x;
  const int w = tid >> 6, l = tid & 63;
  const int lq = l & 31, h = l >> 5;
  const int bx = blockIdx.x;
  int i, hf;
  if constexpr (SPLIT){
    int u = bx >> 5, v = u & 15;
    i = (v < 8) ? 15 - v : v - 8;
    hf = u >> 4;
  } else {
    i = (bx < 256) ? 15 - (bx >> 5) : (bx >> 5) - 8;
    hf = 0;
  }
  const int bh = bx & 31;
  const int q0 = i * 128, qw = q0 + w * 32;
  const int t0 = (SPLIT && hf) ? (i + 1) : 0;
  const int t1 = (SPLIT && !hf) ? (i + 1) : 2 * (i + 1);

  // Q fragments (B-operand): qb[dk] = Q[qw+lq][16*dk + 8*h .. +7]
  bf16x8 qb[4];
  {
    const short* qbase = Q + (bh * T_ + qw + lq) * HD_;
#pragma unroll
    for (int dk = 0; dk < 4; dk++)
      qb[dk] = *(const bf16x8*)(qbase + dk * 16 + h * 8);
  }

  f32x16 o0 = {}, o1 = {};
  float m = -1e30f, ll = 0.f;

  auto stage = [&](int buf, int t){
#pragma unroll
    for (int j = 0; j < 2; j++){
      int idx = j * 256 + tid;
      int row = idx >> 3, cb = (idx & 7) * 16;     // 128B rows
      int cbs = cb ^ ((row & 7) << 4);
      gl2lds16(Kg + (bh * T_ + t * 64 + row) * HD_ + (cbs >> 1), (char*)Ks[buf] + idx * 16);
      gl2lds16(Vt + (bh * HD_ + row) * T_ + t * 64 + (cbs >> 1), (char*)Vs[buf] + idx * 16);
    }
  };

  stage(0, t0);
  for (int t = t0; t < t1; ++t){
    const int cur = (t - t0) & 1;
    if (t + 1 < t1){
      stage(cur ^ 1, t + 1);                            // prefetch next tile
      asm volatile("s_waitcnt vmcnt(4)" ::: "memory");  // current tile landed
    } else {
      asm volatile("s_waitcnt vmcnt(0)" ::: "memory");
    }
    __builtin_amdgcn_s_barrier();
    __builtin_amdgcn_sched_barrier(0);

    const int kvb = t * 64;
    if (kvb <= qw + 31){                  // warp still below/on its diagonal
      const short* Kc = Ks[cur];
      const short* Vc = Vs[cur];

      // S^T = K . Q^T : s[kb] covers kv [kvb+32*kb, +32), q col = lq
      f32x16 s[2] = {};
      __builtin_amdgcn_s_setprio(1);
#pragma unroll
      for (int kb = 0; kb < 2; kb++){
        int row = kb * 32 + lq;
        const char* rp = (const char*)Kc + row * 128;
        int swz = (row & 7) << 4;
#pragma unroll
        for (int dk = 0; dk < 4; dk++){
          bf16x8 ka = *(const bf16x8*)(rp + ((dk * 32 + h * 16) ^ swz));
          s[kb] = __builtin_amdgcn_mfma_f32_32x32x16_bf16(ka, qb[dk], s[kb], 0, 0, 0);
        }
      }
      __builtin_amdgcn_s_setprio(0);

      const int qg = qw + lq;
      if (kvb + 63 > qw){                 // diagonal tile: causal mask
#pragma unroll
        for (int kb = 0; kb < 2; kb++)
#pragma unroll
          for (int r = 0; r < 16; r++){
            int kv = kvb + kb * 32 + crow(r, h);
            if (kv > qg) s[kb][r] = -1e30f;
          }
      }

      // row max: lane-local + 1 cross-half shuffle
      float pm = s[0][0];
#pragma unroll
      for (int r = 1; r < 16; r++) pm = fmaxf(pm, s[0][r]);
#pragma unroll
      for (int r = 0; r < 16; r++) pm = fmaxf(pm, s[1][r]);
      pm = fmaxf(pm, __shfl_xor(pm, 32));

      // defer-max (T13): rescale O only when max grew > 8 (log2 domain)
      if (__any(pm > m + 8.f)){
        float mn = fmaxf(pm, m);
        float sf = __builtin_amdgcn_exp2f(m - mn);
        m = mn;
        ll *= sf;
        bounce[w][lq] = sf;               // lanes l and l+32 write same value
#pragma unroll
        for (int r = 0; r < 16; r++){
          float sr = bounce[w][crow(r, h)];
          o0[r] *= sr; o1[r] *= sr;
        }
      }

      // P = 2^(s - m); row sum
      float ts = 0.f;
#pragma unroll
      for (int kb = 0; kb < 2; kb++)
#pragma unroll
        for (int r = 0; r < 16; r++){
          float p = __builtin_amdgcn_exp2f(s[kb][r] - m);
          s[kb][r] = p;
          ts += p;
        }
      ts += __shfl_xor(ts, 32);
      ll += ts;

      // pack P to bf16 pairs; pw0[kb*4+g] = kv kb*32+8g+4h'+{0,1}, pw1: +{2,3}
      unsigned pw0[8], pw1[8];
#pragma unroll
      for (int kb = 0; kb < 2; kb++)
#pragma unroll
        for (int gg = 0; gg < 4; gg++){
          unsigned r0, r1;
          asm("v_cvt_pk_bf16_f32 %0, %1, %2" : "=v"(r0) : "v"(s[kb][gg * 4 + 0]), "v"(s[kb][gg * 4 + 1]));
          asm("v_cvt_pk_bf16_f32 %0, %1, %2" : "=v"(r1) : "v"(s[kb][gg * 4 + 2]), "v"(s[kb][gg * 4 + 3]));
          pw0[kb * 4 + gg] = r0;
          pw1[kb * 4 + gg] = r1;
        }
      // swap(D=even, S=odd): D_hi <-> S_lo. even reg -> A-word0, odd -> A-word2.
#pragma unroll
      for (int ks = 0; ks < 4; ks++){
        asm("v_permlane32_swap_b32 %0, %1" : "+v"(pw0[2 * ks]), "+v"(pw0[2 * ks + 1]));
        asm("v_permlane32_swap_b32 %0, %1" : "+v"(pw1[2 * ks]), "+v"(pw1[2 * ks + 1]));
      }

      // O += P @ V
      __builtin_amdgcn_s_setprio(1);
#pragma unroll
      for (int ks = 0; ks < 4; ks++){
        uint4v paw;
        paw[0] = pw0[2 * ks];     paw[1] = pw1[2 * ks];
        paw[2] = pw0[2 * ks + 1]; paw[3] = pw1[2 * ks + 1];
        bf16x8 pa = __builtin_bit_cast(bf16x8, paw);
#pragma unroll
        for (int nb = 0; nb < 2; nb++){
          int row = nb * 32 + lq;
          bf16x8 vb = *(const bf16x8*)((const char*)Vc + row * 128 +
                        ((ks * 32 + h * 16) ^ ((row & 7) << 4)));
          if (nb == 0) o0 = __builtin_amdgcn_mfma_f32_32x32x16_bf16(pa, vb, o0, 0, 0, 0);
          else         o1 = __builtin_amdgcn_mfma_f32_32x32x16_bf16(pa, vb, o1, 0, 0, 0);
        }
      }
      __builtin_amdgcn_s_setprio(0);
    }
    __builtin_amdgcn_sched_barrier(0);
    __builtin_amdgcn_s_barrier();        // all reads of buf[cur] done
  }

  if constexpr (SPLIT){
    // store unnormalized partials (f32) + per-row (m, l)
    float* Oq = Op + ((size_t)(hf * 32 + bh)) * (size_t)T_ * 64;
    if (h == 0){
      float* mlr = ml + ((size_t)(hf * 32 + bh) * T_ + (qw + lq)) * 2;
      mlr[0] = m; mlr[1] = ll;
    }
#pragma unroll
    for (int r = 0; r < 16; r++){
      int qg = qw + crow(r, h);
      Oq[qg * 64 + lq]      = o0[r];
      Oq[qg * 64 + 32 + lq] = o1[r];
    }
  } else {
    // normalize by 1/l (broadcast via warp-private LDS) and store
    bounce[w][lq] = __builtin_amdgcn_rcpf(ll);
    const int b = bh >> 4, hh = bh & 15;
#pragma unroll
    for (int r = 0; r < 16; r++){
      int row = crow(r, h);
      float rl = bounce[w][row];
      int qg = qw + row;
      short* yb = Y + (b * T_ + qg) * D_ + hh * 64;
      yb[lq]      = f2bf(o0[r] * rl);
      yb[32 + lq] = f2bf(o1[r] * rl);
    }
  }
}

// ---------------- merge the two kv-split halves ----------------
__global__ __launch_bounds__(256) void attn_merge(
    const float* __restrict__ Op, const float* __restrict__ ml,
    short* __restrict__ Y){
  int gid = blockIdx.x * 256 + threadIdx.x;
  int rid = gid >> 2, c16 = (gid & 3) * 16;
  float m1 = ml[rid * 2],           l1 = ml[rid * 2 + 1];
  float m2 = ml[131072 + rid * 2],  l2 = ml[131072 + rid * 2 + 1];
  float M  = fmaxf(m1, m2);
  float f1 = __builtin_amdgcn_exp2f(m1 - M);
  float f2 = __builtin_amdgcn_exp2f(m2 - M);
  float rl = 1.f / (f1 * l1 + f2 * l2);
  f1 *= rl; f2 *= rl;
  const float4* O1 = (const float4*)(Op + (size_t)rid * 64 + c16);
  const float4* O2 = (const float4*)(Op + 4194304ull + (size_t)rid * 64 + c16);
  int bh = rid >> 11, t = rid & 2047;
  short* yb = Y + (((bh >> 4) * T_ + t) * D_) + (bh & 15) * 64 + c16;
#pragma unroll
  for (int j = 0; j < 4; j++){
    float4 a = O1[j], b = O2[j];
    short4v o;
    o[0] = f2bf(f1 * a.x + f2 * b.x);
    o[1] = f2bf(f1 * a.y + f2 * b.y);
    o[2] = f2bf(f1 * a.z + f2 * b.z);
    o[3] = f2bf(f1 * a.w + f2 * b.w);
    *(short4v*)(yb + j * 4) = o;
  }
}

// ---------------- launch ----------------
extern "C" void kernel_launch(void* const* d_in, const int* in_sizes, int n_in,
                              void* d_out, int out_size, void* d_ws, size_t ws_size,
                              hipStream_t stream) {
  const float* x  = (const float*)d_in[0];
  const float* W1 = (const float*)d_in[1];
  const float* b1 = (const float*)d_in[2];
  const float* W2 = (const float*)d_in[3];
  const float* b2 = (const float*)d_in[4];
  float* out = (float*)d_out;

  char* ws = (char*)d_ws;
  short* W1T = (short*)(ws);                         // [3072][1024] bf16, 6 MB
  short* W2T = (short*)(ws + 6291456);               // [1024][1024] bf16, 2 MB
  short* xb  = (short*)(ws + 8388608);               // [4096][1024] bf16, 8 MB
  short* q   = (short*)(ws + 16777216);              // [B,H,T,64]  bf16, 8 MB
  short* kk  = (short*)(ws + 25165824);              // [B,H,T,64]  bf16, 8 MB
  short* vT  = (short*)(ws + 33554432);              // [B,H,64,T]  bf16, 8 MB
  float* Op  = (float*)(ws + 41943040);              // [2][32][2048][64] f32, 32 MB
  float* mlb = (float*)(ws + 41943040 + 33554432);   // [2][32][2048][2]  f32, 1 MB
  short* y   = xb;                                   // alias: xb dead after QKV GEMM

  const size_t need = 41943040ull + 33554432ull + 1048576ull;
  const bool split = ws_size >= need;

  prep<<<dim3(8192), dim3(256), 0, stream>>>(x, xb, W1, W1T, W2, W2T);
  gemm_bt<3072, 1024, 0><<<dim3(24, 32), dim3(256), 0, stream>>>(xb, W1T, b1, q, kk, vT, nullptr);
  if (split){
    attn32<1><<<dim3(1024), dim3(256), 0, stream>>>(q, kk, vT, nullptr, Op, mlb);
    attn_merge<<<dim3(1024), dim3(256), 0, stream>>>(Op, mlb, y);
  } else {
    attn32<0><<<dim3(512), dim3(256), 0, stream>>>(q, kk, vT, y, nullptr, nullptr);
  }
  gemm_bt<1024, 1024, 1><<<dim3(8, 32), dim3(256), 0, stream>>>(y, W2T, b2, nullptr, nullptr, nullptr, out);
}

// Round 10
// 111.507 us; speedup vs baseline: 1.2594x; 1.0424x over previous
//
#include <hip/hip_runtime.h>

typedef __attribute__((ext_vector_type(8))) short bf16x8;
typedef __attribute__((ext_vector_type(4))) float f32x4;
typedef __attribute__((ext_vector_type(16))) float f32x16;
typedef __attribute__((ext_vector_type(4))) short short4v;
typedef __attribute__((ext_vector_type(4))) unsigned int uint4v;

#define B_  2
#define T_  2048
#define D_  1024
#define H_  16
#define HD_ 64

__device__ inline short f2bf(float f){
  unsigned u = __builtin_bit_cast(unsigned, f);
  u += 0x7fff + ((u >> 16) & 1);          // round-to-nearest-even
  return (short)(u >> 16);
}
__device__ inline float bf2f(short s){
  unsigned u = ((unsigned)(unsigned short)s) << 16;
  return __builtin_bit_cast(float, u);
}

__device__ inline void gl2lds16(const void* g, void* l){
  __builtin_amdgcn_global_load_lds(
      (const __attribute__((address_space(1))) unsigned int*)g,
      (__attribute__((address_space(3))) unsigned int*)l, 16, 0, 0);
}

// ---------------- fused prep: x->bf16, W1->W1T bf16, W2->W2T bf16 ----------
__device__ inline void transpose_tile(const float* __restrict__ in,
                                      short* __restrict__ out,
                                      int R, int C, int bx, int by){
  __shared__ float tile[32][33];
  int tx = threadIdx.x & 31, ty0 = threadIdx.x >> 5;
#pragma unroll
  for (int i = 0; i < 4; i++){
    int ty = ty0 + i * 8;
    tile[ty][tx] = in[(by + ty) * C + bx + tx];
  }
  __syncthreads();
#pragma unroll
  for (int i = 0; i < 4; i++){
    int ty = ty0 + i * 8;
    out[(bx + ty) * R + by + tx] = f2bf(tile[tx][ty]);
  }
}

__global__ __launch_bounds__(256) void prep(
    const float* __restrict__ x,  short* __restrict__ xb,
    const float* __restrict__ W1, short* __restrict__ W1T,
    const float* __restrict__ W2, short* __restrict__ W2T){
  const int bid = blockIdx.x;
  if (bid < 4096){
    int i = (bid * 256 + threadIdx.x) * 4;
    float4 v = *(const float4*)(x + i);
    short4v o;
    o[0] = f2bf(v.x); o[1] = f2bf(v.y); o[2] = f2bf(v.z); o[3] = f2bf(v.w);
    *(short4v*)(xb + i) = o;
  } else if (bid < 4096 + 3072){
    int tb = bid - 4096;                       // W1 [1024][3072] -> W1T
    transpose_tile(W1, W1T, 1024, 3072, (tb % 96) << 5, (tb / 96) << 5);
  } else {
    int tb = bid - 7168;                       // W2 [1024][1024] -> W2T
    transpose_tile(W2, W2T, 1024, 1024, (tb % 32) << 5, (tb / 32) << 5);
  }
}

// ---------------- GEMM: C = A[M][K] @ Bt[N][K]^T + bias ----------------
// 3-buffer LDS, one barrier per K-iter (round-9 structure; ~620 TF at this
// shape — three pipeline variants plateaued here; shape-bound per m102 curve).
#define BM 128
#define BN 128
#define BK 32

// Q pre-scale: 1/sqrt(64) * log2(e)  (softmax runs in exp2 domain)
#define QSCALE 0.18033688011112042f

template<int N_, int K_, int EPI>
__global__ __launch_bounds__(256, 3) void gemm_bt(
    const short* __restrict__ A, const short* __restrict__ Bt,
    const float* __restrict__ bias,
    short* __restrict__ q, short* __restrict__ kk, short* __restrict__ vT,
    float* __restrict__ outf){
  __shared__ short As[3][BM * BK];
  __shared__ short Bs[3][BN * BK];
  const int tid = threadIdx.x;
  const int lane = tid & 63, w = tid >> 6;
  const int wm = w >> 1, wn = w & 1;
  const int lr = lane & 15, lk = lane >> 4;
  const int brow = blockIdx.y * BM, bcol = blockIdx.x * BN;
  f32x4 acc[4][4] = {};
  const short* Ag = A  + brow * K_;
  const short* Bg = Bt + bcol * K_;

  auto stage = [&](int buf, int k0){
#pragma unroll
    for (int i = 0; i < 2; i++){
      int idx = i * 256 + tid;
      int row = idx >> 2, c8 = (idx & 3) * 8;   // 64B rows of 32 bf16
      gl2lds16(Ag + row * K_ + k0 + c8, (char*)As[buf] + idx * 16);
      gl2lds16(Bg + row * K_ + k0 + c8, (char*)Bs[buf] + idx * 16);
    }
  };

  const int NT = K_ / BK;
  stage(0, 0);
  stage(1, BK);
  for (int t = 0; t < NT; ++t){
    if (t + 1 < NT)
      asm volatile("s_waitcnt vmcnt(4)" ::: "memory");  // tile t landed (mine)
    else
      asm volatile("s_waitcnt vmcnt(0)" ::: "memory");
    __builtin_amdgcn_s_barrier();      // all waves: tile t landed, iter t-1 reads done
    __builtin_amdgcn_sched_barrier(0);
    if (t + 2 < NT)
      stage((t + 2) % 3, (t + 2) * BK);        // safe: buf last read at t-1
    __builtin_amdgcn_sched_barrier(0);

    const short* Ac = As[t % 3];
    const short* Bc = Bs[t % 3];
    bf16x8 a[4], b[4];
#pragma unroll
    for (int mf = 0; mf < 4; mf++)
      a[mf] = *(const bf16x8*)(Ac + (wm * 64 + mf * 16 + lr) * BK + lk * 8);
#pragma unroll
    for (int nf = 0; nf < 4; nf++)
      b[nf] = *(const bf16x8*)(Bc + (wn * 64 + nf * 16 + lr) * BK + lk * 8);
    __builtin_amdgcn_s_setprio(1);
#pragma unroll
    for (int mf = 0; mf < 4; mf++)
#pragma unroll
      for (int nf = 0; nf < 4; nf++)
        acc[mf][nf] = __builtin_amdgcn_mfma_f32_16x16x32_bf16(a[mf], b[nf], acc[mf][nf], 0, 0, 0);
    __builtin_amdgcn_s_setprio(0);
    // no end barrier: next iter's top barrier separates reads from restage
  }

  if constexpr (EPI == 0){
    // C/D layout: col = lane&15, row = (lane>>4)*4 + r
#pragma unroll
    for (int nf = 0; nf < 4; nf++){
      int n = bcol + wn * 64 + nf * 16 + lr;
      float bv = bias[n];
      int sec = n >> 10, d = n & 1023, h = d >> 6, hd = d & 63;
#pragma unroll
      for (int mf = 0; mf < 4; mf++){
        int m0 = brow + wm * 64 + mf * 16 + lk * 4;
        int b = m0 >> 11, t0 = m0 & 2047;
        int bh = b * H_ + h;
        if (sec == 0){
#pragma unroll
          for (int r = 0; r < 4; r++)
            q[(bh * T_ + t0 + r) * HD_ + hd] = f2bf((acc[mf][nf][r] + bv) * QSCALE);
        } else if (sec == 1){
#pragma unroll
          for (int r = 0; r < 4; r++)
            kk[(bh * T_ + t0 + r) * HD_ + hd] = f2bf(acc[mf][nf][r] + bv);
        } else {
          float v0 = acc[mf][nf][0] + bv, v1 = acc[mf][nf][1] + bv;
          float v2 = acc[mf][nf][2] + bv, v3 = acc[mf][nf][3] + bv;
          unsigned lo = (unsigned)(unsigned short)f2bf(v0) | ((unsigned)(unsigned short)f2bf(v1) << 16);
          unsigned hi = (unsigned)(unsigned short)f2bf(v2) | ((unsigned)(unsigned short)f2bf(v3) << 16);
          uint2 pk; pk.x = lo; pk.y = hi;
          *(uint2*)(vT + (bh * HD_ + hd) * T_ + t0) = pk;   // v stored transposed [B,H,hd,T]
        }
      }
    }
  } else {
#pragma unroll
    for (int nf = 0; nf < 4; nf++){
      int n = bcol + wn * 64 + nf * 16 + lr;
      float bv = bias[n];
#pragma unroll
      for (int mf = 0; mf < 4; mf++){
        int m0 = brow + wm * 64 + mf * 16 + lk * 4;
#pragma unroll
        for (int r = 0; r < 4; r++)
          outf[(m0 + r) * N_ + n] = acc[mf][nf][r] + bv;
      }
    }
  }
}

// ---------------- causal flash attention, 32x32 swapped-QK^T ----------------
// Q,K: [B*H, T, 64] bf16 (Q pre-scaled by QSCALE => logits in exp2 domain)
// Vt: [B*H, 64, T] bf16.
// NS=4: each q-tile's nt=2(i+1) kv-tiles split into 4 chunks [c*nt/4,(c+1)*nt/4)
//   -> 2048 blocks, max 8 steps each; empty chunks write (m=-1e30,l=0,O=0).
//   Partials: Op bf16 [4][32][2048][64], ml f32 [4][32][2048][2].
//   Per-CU: pairs (15-w0, w0) x 4 chunks = exactly 34 steps, 8 short blocks.
// NS=1: single-pass (fallback), writes Y directly.
__device__ inline int crow(int r, int h){ return (r & 3) + 8 * (r >> 2) + 4 * h; }

template<int NS>
__global__ __launch_bounds__(256, 4) void attn32(
    const short* __restrict__ Q, const short* __restrict__ Kg,
    const short* __restrict__ Vt, short* __restrict__ Y,
    short* __restrict__ Op, float* __restrict__ ml){
  __shared__ short Ks[2][64 * 64];
  __shared__ short Vs[2][64 * 64];
  __shared__ float bounce[4][32];
  const int tid = threadIdx.x;
  const int w = tid >> 6, l = tid & 63;
  const int lq = l & 31, h = l >> 5;
  const int bx = blockIdx.x;
  int i, hf;
  if constexpr (NS == 4){
    int u = bx >> 5, v = u & 15;
    i = (v < 8) ? 15 - v : v - 8;
    hf = u >> 4;
  } else {
    i = (bx < 256) ? 15 - (bx >> 5) : (bx >> 5) - 8;
    hf = 0;
  }
  const int bh = bx & 31;
  const int q0 = i * 128, qw = q0 + w * 32;
  const int nt = 2 * (i + 1);
  const int t0 = hf * nt / NS;
  const int t1 = (hf + 1) * nt / NS;

  // Q fragments (B-operand): qb[dk] = Q[qw+lq][16*dk + 8*h .. +7]
  bf16x8 qb[4];
  {
    const short* qbase = Q + (bh * T_ + qw + lq) * HD_;
#pragma unroll
    for (int dk = 0; dk < 4; dk++)
      qb[dk] = *(const bf16x8*)(qbase + dk * 16 + h * 8);
  }

  f32x16 o0 = {}, o1 = {};
  float m = -1e30f, ll = 0.f;

  auto stage = [&](int buf, int t){
#pragma unroll
    for (int j = 0; j < 2; j++){
      int idx = j * 256 + tid;
      int row = idx >> 3, cb = (idx & 7) * 16;     // 128B rows
      int cbs = cb ^ ((row & 7) << 4);
      gl2lds16(Kg + (bh * T_ + t * 64 + row) * HD_ + (cbs >> 1), (char*)Ks[buf] + idx * 16);
      gl2lds16(Vt + (bh * HD_ + row) * T_ + t * 64 + (cbs >> 1), (char*)Vs[buf] + idx * 16);
    }
  };

  if (t0 < t1){
    stage(0, t0);
    for (int t = t0; t < t1; ++t){
      const int cur = (t - t0) & 1;
      if (t + 1 < t1){
        stage(cur ^ 1, t + 1);                            // prefetch next tile
        asm volatile("s_waitcnt vmcnt(4)" ::: "memory");  // current tile landed
      } else {
        asm volatile("s_waitcnt vmcnt(0)" ::: "memory");
      }
      __builtin_amdgcn_s_barrier();
      __builtin_amdgcn_sched_barrier(0);

      const int kvb = t * 64;
      if (kvb <= qw + 31){                  // warp still below/on its diagonal
        const short* Kc = Ks[cur];
        const short* Vc = Vs[cur];

        // S^T = K . Q^T : s[kb] covers kv [kvb+32*kb, +32), q col = lq
        f32x16 s[2] = {};
        __builtin_amdgcn_s_setprio(1);
#pragma unroll
        for (int kb = 0; kb < 2; kb++){
          int row = kb * 32 + lq;
          const char* rp = (const char*)Kc + row * 128;
          int swz = (row & 7) << 4;
#pragma unroll
          for (int dk = 0; dk < 4; dk++){
            bf16x8 ka = *(const bf16x8*)(rp + ((dk * 32 + h * 16) ^ swz));
            s[kb] = __builtin_amdgcn_mfma_f32_32x32x16_bf16(ka, qb[dk], s[kb], 0, 0, 0);
          }
        }
        __builtin_amdgcn_s_setprio(0);

        const int qg = qw + lq;
        if (kvb + 63 > qw){                 // diagonal tile: causal mask
#pragma unroll
          for (int kb = 0; kb < 2; kb++)
#pragma unroll
            for (int r = 0; r < 16; r++){
              int kv = kvb + kb * 32 + crow(r, h);
              if (kv > qg) s[kb][r] = -1e30f;
            }
        }

        // row max: lane-local + 1 cross-half shuffle
        float pm = s[0][0];
#pragma unroll
        for (int r = 1; r < 16; r++) pm = fmaxf(pm, s[0][r]);
#pragma unroll
        for (int r = 0; r < 16; r++) pm = fmaxf(pm, s[1][r]);
        pm = fmaxf(pm, __shfl_xor(pm, 32));

        // defer-max (T13): rescale O only when max grew > 8 (log2 domain)
        if (__any(pm > m + 8.f)){
          float mn = fmaxf(pm, m);
          float sf = __builtin_amdgcn_exp2f(m - mn);
          m = mn;
          ll *= sf;
          bounce[w][lq] = sf;               // lanes l and l+32 write same value
#pragma unroll
          for (int r = 0; r < 16; r++){
            float sr = bounce[w][crow(r, h)];
            o0[r] *= sr; o1[r] *= sr;
          }
        }

        // P = 2^(s - m); row sum
        float ts = 0.f;
#pragma unroll
        for (int kb = 0; kb < 2; kb++)
#pragma unroll
          for (int r = 0; r < 16; r++){
            float p = __builtin_amdgcn_exp2f(s[kb][r] - m);
            s[kb][r] = p;
            ts += p;
          }
        ts += __shfl_xor(ts, 32);
        ll += ts;

        // pack P to bf16 pairs; pw0[kb*4+g] = kv kb*32+8g+4h'+{0,1}, pw1: +{2,3}
        unsigned pw0[8], pw1[8];
#pragma unroll
        for (int kb = 0; kb < 2; kb++)
#pragma unroll
          for (int gg = 0; gg < 4; gg++){
            unsigned r0, r1;
            asm("v_cvt_pk_bf16_f32 %0, %1, %2" : "=v"(r0) : "v"(s[kb][gg * 4 + 0]), "v"(s[kb][gg * 4 + 1]));
            asm("v_cvt_pk_bf16_f32 %0, %1, %2" : "=v"(r1) : "v"(s[kb][gg * 4 + 2]), "v"(s[kb][gg * 4 + 3]));
            pw0[kb * 4 + gg] = r0;
            pw1[kb * 4 + gg] = r1;
          }
        // swap(D=even, S=odd): D_hi <-> S_lo. even reg -> A-word0, odd -> A-word2.
#pragma unroll
        for (int ks = 0; ks < 4; ks++){
          asm("v_permlane32_swap_b32 %0, %1" : "+v"(pw0[2 * ks]), "+v"(pw0[2 * ks + 1]));
          asm("v_permlane32_swap_b32 %0, %1" : "+v"(pw1[2 * ks]), "+v"(pw1[2 * ks + 1]));
        }

        // O += P @ V
        __builtin_amdgcn_s_setprio(1);
#pragma unroll
        for (int ks = 0; ks < 4; ks++){
          uint4v paw;
          paw[0] = pw0[2 * ks];     paw[1] = pw1[2 * ks];
          paw[2] = pw0[2 * ks + 1]; paw[3] = pw1[2 * ks + 1];
          bf16x8 pa = __builtin_bit_cast(bf16x8, paw);
#pragma unroll
          for (int nb = 0; nb < 2; nb++){
            int row = nb * 32 + lq;
            bf16x8 vb = *(const bf16x8*)((const char*)Vc + row * 128 +
                          ((ks * 32 + h * 16) ^ ((row & 7) << 4)));
            if (nb == 0) o0 = __builtin_amdgcn_mfma_f32_32x32x16_bf16(pa, vb, o0, 0, 0, 0);
            else         o1 = __builtin_amdgcn_mfma_f32_32x32x16_bf16(pa, vb, o1, 0, 0, 0);
          }
        }
        __builtin_amdgcn_s_setprio(0);
      }
      __builtin_amdgcn_sched_barrier(0);
      __builtin_amdgcn_s_barrier();        // all reads of buf[cur] done
    }
  }

  if constexpr (NS == 4){
    // store unnormalized partials (bf16) + per-row (m, l)
    short* Oq = Op + ((size_t)(hf * 32 + bh)) * (size_t)T_ * 64;
    if (h == 0){
      float* mlr = ml + ((size_t)(hf * 32 + bh) * T_ + (qw + lq)) * 2;
      mlr[0] = m; mlr[1] = ll;
    }
#pragma unroll
    for (int r = 0; r < 16; r++){
      int qg = qw + crow(r, h);
      Oq[qg * 64 + lq]      = f2bf(o0[r]);
      Oq[qg * 64 + 32 + lq] = f2bf(o1[r]);
    }
  } else {
    // normalize by 1/l (broadcast via warp-private LDS) and store
    bounce[w][lq] = __builtin_amdgcn_rcpf(ll);
    const int b = bh >> 4, hh = bh & 15;
#pragma unroll
    for (int r = 0; r < 16; r++){
      int row = crow(r, h);
      float rl = bounce[w][row];
      int qg = qw + row;
      short* yb = Y + (b * T_ + qg) * D_ + hh * 64;
      yb[lq]      = f2bf(o0[r] * rl);
      yb[32 + lq] = f2bf(o1[r] * rl);
    }
  }
}

// ---------------- merge the four kv-split chunks ----------------
// Op: bf16 [4][32][2048][64]; ml: f32 [4][32][2048][2]; Y: bf16 [B,T,1024].
// Thread: rid = bh*2048+t, 16 cols.  262144 threads = 1024 blocks.
__global__ __launch_bounds__(256) void attn_merge(
    const short* __restrict__ Op, const float* __restrict__ ml,
    short* __restrict__ Y){
  int gid = blockIdx.x * 256 + threadIdx.x;
  int rid = gid >> 2, c16 = (gid & 3) * 16;
  float mh[4], lh[4];
#pragma unroll
  for (int hf = 0; hf < 4; hf++){
    float2 v = *(const float2*)(ml + (size_t)hf * 131072 + rid * 2);
    mh[hf] = v.x; lh[hf] = v.y;
  }
  float M = fmaxf(fmaxf(mh[0], mh[1]), fmaxf(mh[2], mh[3]));
  float f[4], den = 0.f;
#pragma unroll
  for (int hf = 0; hf < 4; hf++){
    f[hf] = __builtin_amdgcn_exp2f(mh[hf] - M);
    den += f[hf] * lh[hf];
  }
  float rl = 1.f / den;
  float acc[16] = {};
#pragma unroll
  for (int hf = 0; hf < 4; hf++){
    const short* o = Op + (size_t)hf * 4194304 + (size_t)rid * 64 + c16;
    bf16x8 a = *(const bf16x8*)(o);
    bf16x8 b = *(const bf16x8*)(o + 8);
    float fh = f[hf];
#pragma unroll
    for (int j = 0; j < 8; j++){
      acc[j]     += fh * bf2f(a[j]);
      acc[8 + j] += fh * bf2f(b[j]);
    }
  }
  int bh = rid >> 11, t = rid & 2047;
  short* yb = Y + (((bh >> 4) * T_ + t) * D_) + (bh & 15) * 64 + c16;
  bf16x8 o0, o1;
#pragma unroll
  for (int j = 0; j < 8; j++){
    o0[j] = f2bf(acc[j] * rl);
    o1[j] = f2bf(acc[8 + j] * rl);
  }
  *(bf16x8*)(yb)     = o0;
  *(bf16x8*)(yb + 8) = o1;
}

// ---------------- launch ----------------
extern "C" void kernel_launch(void* const* d_in, const int* in_sizes, int n_in,
                              void* d_out, int out_size, void* d_ws, size_t ws_size,
                              hipStream_t stream) {
  const float* x  = (const float*)d_in[0];
  const float* W1 = (const float*)d_in[1];
  const float* b1 = (const float*)d_in[2];
  const float* W2 = (const float*)d_in[3];
  const float* b2 = (const float*)d_in[4];
  float* out = (float*)d_out;

  char* ws = (char*)d_ws;
  short* W1T = (short*)(ws);                         // [3072][1024] bf16, 6 MB
  short* W2T = (short*)(ws + 6291456);               // [1024][1024] bf16, 2 MB
  short* xb  = (short*)(ws + 8388608);               // [4096][1024] bf16, 8 MB
  short* q   = (short*)(ws + 16777216);              // [B,H,T,64]  bf16, 8 MB
  short* kk  = (short*)(ws + 25165824);              // [B,H,T,64]  bf16, 8 MB
  short* vT  = (short*)(ws + 33554432);              // [B,H,64,T]  bf16, 8 MB
  short* Op  = (short*)(ws + 41943040);              // [4][32][2048][64] bf16, 32 MB
  float* mlb = (float*)(ws);                         // [4][32][2048][2] f32, 2 MB
                                                     //   overlays W1T (dead after QKV)
  short* y   = xb;                                   // alias: xb dead after QKV GEMM

  const size_t need = 41943040ull + 33554432ull;     // 72 MB
  const bool split = ws_size >= need;

  prep<<<dim3(8192), dim3(256), 0, stream>>>(x, xb, W1, W1T, W2, W2T);
  gemm_bt<3072, 1024, 0><<<dim3(24, 32), dim3(256), 0, stream>>>(xb, W1T, b1, q, kk, vT, nullptr);
  if (split){
    attn32<4><<<dim3(2048), dim3(256), 0, stream>>>(q, kk, vT, nullptr, Op, mlb);
    attn_merge<<<dim3(1024), dim3(256), 0, stream>>>(Op, mlb, y);
  } else {
    attn32<1><<<dim3(512), dim3(256), 0, stream>>>(q, kk, vT, y, nullptr, nullptr);
  }
  gemm_bt<1024, 1024, 1><<<dim3(8, 32), dim3(256), 0, stream>>>(y, W2T, b2, nullptr, nullptr, nullptr, out);
}